// Round 12
// baseline (111.584 us; speedup 1.0000x reference)
//
#include <hip/hip_runtime.h>
#include <hip/hip_bf16.h>

#define N_NODES 50000
#define N_EDGES 600000
#define BN_EPS 1e-5f
#define ELL_MAX 64          // per-node list cap; P(deg>=64) ~ 1e-30
#define N_BUCKETS 782       // ceil(50000/64) 64-node tiles
#define BUCKET_CAP 1024     // lambda=768, sigma=27.7 -> +9.2 sigma

#define EPT 8               // edges per thread in the binning blocks
#define EB_EDGES (256 * EPT)                    // 2048
#define N_EB ((N_EDGES + EB_EDGES - 1) / EB_EDGES)   // 293
#define N_CONV_BLK 6250                         // 1.6M threads / 256
#define N_W_BLK 192                             // 49152 / 256
#define PREP_GRID (N_EB + N_CONV_BLK + N_W_BLK + 1)

typedef short bf16x8 __attribute__((ext_vector_type(8)));
typedef float f32x4 __attribute__((ext_vector_type(4)));

__device__ __forceinline__ ushort f2bf(float f) {
    unsigned u = __float_as_uint(f);
    u += 0x7fffu + ((u >> 16) & 1u);
    return (ushort)(u >> 16);
}
__device__ __forceinline__ float bf_lo(unsigned u) { return __uint_as_float(u << 16); }
__device__ __forceinline__ float bf_hi(unsigned u) { return __uint_as_float(u & 0xffff0000u); }

// ===========================================================================
// zero_bcnt: hand-rolled (runtime tiny-fill path avoided).
// ===========================================================================
__global__ __launch_bounds__(256) void zero_bcnt_kernel(int* __restrict__ bcnt) {
    int t = blockIdx.x * 256 + threadIdx.x;
    if (t < N_BUCKETS) bcnt[t] = 0;
}

// ===========================================================================
// prep_scatter (block-range partitioned):
//   blocks [0, N_EB): LDS-aggregated edge binning, 2048 edges/block.
//   blocks [N_EB, +6250): x -> bf16 (Xb).
//   blocks [.., +192): weight transpose W1T / W2T2.
//   last block: bn fold.
// ===========================================================================
__global__ __launch_bounds__(256) void prep_scatter_kernel(
    const float* __restrict__ x, const int* __restrict__ eidx,
    const float* __restrict__ W1l, const float* __restrict__ W1r,
    const float* __restrict__ W2l, const float* __restrict__ W2r,
    const float* __restrict__ gamma, const float* __restrict__ beta,
    const float* __restrict__ mean, const float* __restrict__ var,
    const float* __restrict__ b1,
    ushort* __restrict__ Xb, ushort* __restrict__ W1T, ushort* __restrict__ W2T2,
    float* __restrict__ scale_, float* __restrict__ shift_,
    int* __restrict__ bcnt, unsigned* __restrict__ bucket) {
    const int blk = blockIdx.x;
    const int tid = threadIdx.x;

    if (blk < N_EB) {
        __shared__ int lcnt[N_BUCKETS];
        __shared__ int lbase[N_BUCKETS];
        const int e0 = blk * EB_EDGES;
        const int n = (N_EDGES - e0) < EB_EDGES ? (N_EDGES - e0) : EB_EDGES;

        for (int i = tid; i < N_BUCKETS; i += 256) lcnt[i] = 0;
        __syncthreads();

        // E1: histogram + rank; keep pk and packed src in registers
        unsigned pk[EPT];
        unsigned sp[EPT / 2];
        #pragma unroll
        for (int i = 0; i < EPT; ++i) {
            int idx = i * 256 + tid;
            if (idx < n) {
                int src = eidx[e0 + idx];
                int dst = eidx[N_EDGES + e0 + idx];
                int b = dst >> 6;
                int r = atomicAdd(&lcnt[b], 1);
                pk[i] = ((unsigned)b << 17) | ((unsigned)r << 6) | (unsigned)(dst & 63);
                if (i & 1) sp[i >> 1] |= ((unsigned)src << 16);
                else       sp[i >> 1]  = (unsigned)src & 0xFFFFu;
            } else {
                pk[i] = 0xFFFFFFFFu;
            }
        }
        __syncthreads();

        // E2: one global atomic per non-empty bin
        for (int i = tid; i < N_BUCKETS; i += 256) {
            int c = lcnt[i];
            lbase[i] = c ? atomicAdd(&bcnt[i], c) : 0;
        }
        __syncthreads();

        // E3: grouped scatter from registers
        #pragma unroll
        for (int i = 0; i < EPT; ++i) {
            if (pk[i] != 0xFFFFFFFFu) {
                int b = pk[i] >> 17;
                int r = (pk[i] >> 6) & 0x7FF;
                int dl = pk[i] & 63;
                unsigned src = (i & 1) ? (sp[i >> 1] >> 16) : (sp[i >> 1] & 0xFFFFu);
                int p = lbase[b] + r;
                if (p < BUCKET_CAP)
                    bucket[(size_t)b * BUCKET_CAP + p] = (src << 6) | (unsigned)dl;
            }
        }
    } else if (blk < N_EB + N_CONV_BLK) {
        int t = (blk - N_EB) * 256 + tid;           // < 1,600,000
        int row = t >> 5, c4 = t & 31;
        float4 v = *(const float4*)(x + (size_t)row * 128 + c4 * 4);
        ushort4 o;
        o.x = f2bf(v.x); o.y = f2bf(v.y); o.z = f2bf(v.z); o.w = f2bf(v.w);
        *(ushort4*)(Xb + (size_t)row * 128 + c4 * 4) = o;
    } else if (blk < N_EB + N_CONV_BLK + N_W_BLK) {
        int t2 = (blk - N_EB - N_CONV_BLK) * 256 + tid;   // < 49152
        if (t2 < 128 * 256) {
            int c = t2 >> 8, k = t2 & 255;
            float v = (k < 128) ? W1l[k * 128 + c] : W1r[(k - 128) * 128 + c];
            W1T[c * 256 + k] = f2bf(v);
        } else {
            int t3 = t2 - 128 * 256;            // 0..16383
            int c = t3 >> 7, k = t3 & 127;
            float v = (c < 64) ? W2l[k * 64 + c] : W2r[k * 64 + (c - 64)];
            W2T2[c * 128 + k] = f2bf(v);
        }
    } else {
        if (tid < 128) {
            int c = tid;
            float sc = gamma[c] * rsqrtf(var[c] + BN_EPS);
            scale_[c] = sc;
            shift_[c] = sc * (b1[c] - mean[c]) + beta[c];
        }
    }
}

// ===========================================================================
// gather1: one block per QUARTER-bucket (16 nodes). Scan the bucket's list
// into a 2KB LDS 16-node list, then gather-mean from Xb (R10 loop form:
// 8-deep / 4-deep / singles -- R11's clamped-16 was a null result).
// ===========================================================================
__global__ __launch_bounds__(256) void gather1_kernel(
    const ushort* __restrict__ Xb, const unsigned* __restrict__ bucket,
    const int* __restrict__ bcnt, ushort* __restrict__ Agg) {
    __shared__ ushort lell[16 * ELL_MAX];   // 2 KB
    __shared__ int lcnt[16];
    const int tid = threadIdx.x;
    const int bkt = blockIdx.x >> 2, q = blockIdx.x & 3;

    if (tid < 16) lcnt[tid] = 0;
    int n = bcnt[bkt];
    if (n > BUCKET_CAP) n = BUCKET_CAP;
    __syncthreads();
    for (int i = tid; i < n; i += 256) {
        unsigned u = bucket[(size_t)bkt * BUCKET_CAP + i];
        int dl = u & 63;
        if ((dl >> 4) == q) {
            int r = dl & 15;
            int p = atomicAdd(&lcnt[r], 1);
            if (p < ELL_MAX) lell[(r << 6) + p] = (ushort)(u >> 6);
        }
    }
    __syncthreads();

    const int grp = tid >> 4, lane16 = tid & 15;
    const int node = (bkt << 6) + (q << 4) + grp;
    if (node >= N_NODES) return;
    const int dg = lcnt[grp];
    const int end = dg < ELL_MAX ? dg : ELL_MAX;
    const ushort* Lp = lell + (grp << 6);
    float a0 = 0.f, a1 = 0.f, a2 = 0.f, a3 = 0.f;
    float a4 = 0.f, a5 = 0.f, a6 = 0.f, a7 = 0.f;
    int j = 0;
    for (; j + 8 <= end; j += 8) {
        ushort4 sa = *(const ushort4*)(Lp + j);
        ushort4 sb = *(const ushort4*)(Lp + j + 4);
        uint4 u0 = *(const uint4*)(Xb + ((size_t)sa.x << 7) + lane16 * 8);
        uint4 u1 = *(const uint4*)(Xb + ((size_t)sa.y << 7) + lane16 * 8);
        uint4 u2 = *(const uint4*)(Xb + ((size_t)sa.z << 7) + lane16 * 8);
        uint4 u3 = *(const uint4*)(Xb + ((size_t)sa.w << 7) + lane16 * 8);
        uint4 u4 = *(const uint4*)(Xb + ((size_t)sb.x << 7) + lane16 * 8);
        uint4 u5 = *(const uint4*)(Xb + ((size_t)sb.y << 7) + lane16 * 8);
        uint4 u6 = *(const uint4*)(Xb + ((size_t)sb.z << 7) + lane16 * 8);
        uint4 u7 = *(const uint4*)(Xb + ((size_t)sb.w << 7) + lane16 * 8);
        a0 += bf_lo(u0.x) + bf_lo(u1.x) + bf_lo(u2.x) + bf_lo(u3.x)
            + bf_lo(u4.x) + bf_lo(u5.x) + bf_lo(u6.x) + bf_lo(u7.x);
        a1 += bf_hi(u0.x) + bf_hi(u1.x) + bf_hi(u2.x) + bf_hi(u3.x)
            + bf_hi(u4.x) + bf_hi(u5.x) + bf_hi(u6.x) + bf_hi(u7.x);
        a2 += bf_lo(u0.y) + bf_lo(u1.y) + bf_lo(u2.y) + bf_lo(u3.y)
            + bf_lo(u4.y) + bf_lo(u5.y) + bf_lo(u6.y) + bf_lo(u7.y);
        a3 += bf_hi(u0.y) + bf_hi(u1.y) + bf_hi(u2.y) + bf_hi(u3.y)
            + bf_hi(u4.y) + bf_hi(u5.y) + bf_hi(u6.y) + bf_hi(u7.y);
        a4 += bf_lo(u0.z) + bf_lo(u1.z) + bf_lo(u2.z) + bf_lo(u3.z)
            + bf_lo(u4.z) + bf_lo(u5.z) + bf_lo(u6.z) + bf_lo(u7.z);
        a5 += bf_hi(u0.z) + bf_hi(u1.z) + bf_hi(u2.z) + bf_hi(u3.z)
            + bf_hi(u4.z) + bf_hi(u5.z) + bf_hi(u6.z) + bf_hi(u7.z);
        a6 += bf_lo(u0.w) + bf_lo(u1.w) + bf_lo(u2.w) + bf_lo(u3.w)
            + bf_lo(u4.w) + bf_lo(u5.w) + bf_lo(u6.w) + bf_lo(u7.w);
        a7 += bf_hi(u0.w) + bf_hi(u1.w) + bf_hi(u2.w) + bf_hi(u3.w)
            + bf_hi(u4.w) + bf_hi(u5.w) + bf_hi(u6.w) + bf_hi(u7.w);
    }
    for (; j + 4 <= end; j += 4) {
        ushort4 sa = *(const ushort4*)(Lp + j);
        uint4 u0 = *(const uint4*)(Xb + ((size_t)sa.x << 7) + lane16 * 8);
        uint4 u1 = *(const uint4*)(Xb + ((size_t)sa.y << 7) + lane16 * 8);
        uint4 u2 = *(const uint4*)(Xb + ((size_t)sa.z << 7) + lane16 * 8);
        uint4 u3 = *(const uint4*)(Xb + ((size_t)sa.w << 7) + lane16 * 8);
        a0 += bf_lo(u0.x) + bf_lo(u1.x) + bf_lo(u2.x) + bf_lo(u3.x);
        a1 += bf_hi(u0.x) + bf_hi(u1.x) + bf_hi(u2.x) + bf_hi(u3.x);
        a2 += bf_lo(u0.y) + bf_lo(u1.y) + bf_lo(u2.y) + bf_lo(u3.y);
        a3 += bf_hi(u0.y) + bf_hi(u1.y) + bf_hi(u2.y) + bf_hi(u3.y);
        a4 += bf_lo(u0.z) + bf_lo(u1.z) + bf_lo(u2.z) + bf_lo(u3.z);
        a5 += bf_hi(u0.z) + bf_hi(u1.z) + bf_hi(u2.z) + bf_hi(u3.z);
        a6 += bf_lo(u0.w) + bf_lo(u1.w) + bf_lo(u2.w) + bf_lo(u3.w);
        a7 += bf_hi(u0.w) + bf_hi(u1.w) + bf_hi(u2.w) + bf_hi(u3.w);
    }
    for (; j < end; ++j) {
        int s = Lp[j];
        uint4 u = *(const uint4*)(Xb + ((size_t)s << 7) + lane16 * 8);
        a0 += bf_lo(u.x); a1 += bf_hi(u.x);
        a2 += bf_lo(u.y); a3 += bf_hi(u.y);
        a4 += bf_lo(u.z); a5 += bf_hi(u.z);
        a6 += bf_lo(u.w); a7 += bf_hi(u.w);
    }
    float ic = 1.0f / fmaxf((float)dg, 1.0f);
    uint4 o;
    o.x = (unsigned)f2bf(a0 * ic) | ((unsigned)f2bf(a1 * ic) << 16);
    o.y = (unsigned)f2bf(a2 * ic) | ((unsigned)f2bf(a3 * ic) << 16);
    o.z = (unsigned)f2bf(a4 * ic) | ((unsigned)f2bf(a5 * ic) << 16);
    o.w = (unsigned)f2bf(a6 * ic) | ((unsigned)f2bf(a7 * ic) << 16);
    *(uint4*)(Agg + ((size_t)node << 7) + lane16 * 8) = o;
}

// ===========================================================================
// mm: 16-ROW tiles, 3125 blocks x 256 thr (4 waves), 8KB LDS.
// R11 lesson: the 64-row version was latency-starved (40.5us, Occ 22%,
// MfmaUtil 4%) -- only 3128 waves and <2 blocks/CU to hide L2-latency
// W-loads. 16-row tiling: 12500 waves (full residency), 8 blocks/CU.
// Wave w owns output cols [32w, 32w+32) in both MFMAs.
// ===========================================================================
__global__ __launch_bounds__(256) void mm_kernel(
    const ushort* __restrict__ Agg, const ushort* __restrict__ Xb,
    const ushort* __restrict__ W1T, const ushort* __restrict__ W2T2,
    const float* __restrict__ scale_, const float* __restrict__ shift_,
    const float* __restrict__ b2,
    ushort* __restrict__ Q, float* __restrict__ R) {
    __shared__ unsigned sAd[16 * 32 * 4];   // 8 KB
    const int tid = threadIdx.x;
    const int row0 = blockIdx.x * 16;

    // stage: 512 granules; gx<16 <- Agg (K 0..127), else <- Xb (K 128..255)
    #pragma unroll
    for (int i = 0; i < 2; ++i) {
        int g = i * 256 + tid;
        int r = g >> 5, gx = g & 31;
        int row = row0 + r;
        uint4 v = make_uint4(0, 0, 0, 0);
        if (row < N_NODES) {
            const ushort* src = (gx < 16)
                ? (Agg + ((size_t)row << 7) + gx * 8)
                : (Xb + ((size_t)row << 7) + (gx - 16) * 8);
            v = *(const uint4*)src;
        }
        *(uint4*)&sAd[((r << 5) + (gx ^ (r & 7))) << 2] = v;
    }
    __syncthreads();

    const bf16x8* sA8 = (const bf16x8*)sAd;
    const int w = tid >> 6, l = tid & 63;
    const int wc = w << 5;              // 0,32,64,96
    const int lr = l & 15, lk = l >> 4;

    f32x4 acc[2];
    acc[0] = (f32x4){0.f, 0.f, 0.f, 0.f};
    acc[1] = (f32x4){0.f, 0.f, 0.f, 0.f};

    #pragma unroll
    for (int kk = 0; kk < 8; ++kk) {
        bf16x8 a = sA8[(lr << 5) + ((kk * 4 + lk) ^ (lr & 7))];
        #pragma unroll
        for (int ni = 0; ni < 2; ++ni) {
            int c = wc + ni * 16 + lr;
            bf16x8 b = *(const bf16x8*)(W1T + (size_t)c * 256 + kk * 32 + lk * 8);
            acc[ni] = __builtin_amdgcn_mfma_f32_16x16x32_bf16(b, a, acc[ni], 0, 0, 0);
        }
    }
    __syncthreads();   // all sA reads done before H overwrites low 4KB

    // bn+relu, H (bf16) -> sH = sAd[0..4KB), [16 r][16 g] swizzled
    #pragma unroll
    for (int ni = 0; ni < 2; ++ni) {
        int c0 = wc + ni * 16 + lk * 4;
        float4 sc = *(const float4*)(scale_ + c0);
        float4 sh = *(const float4*)(shift_ + c0);
        int g = c0 >> 3;
        int sub = (c0 & 4) ? 8 : 0;
        float h0 = fmaxf(acc[ni][0] * sc.x + sh.x, 0.f);
        float h1 = fmaxf(acc[ni][1] * sc.y + sh.y, 0.f);
        float h2 = fmaxf(acc[ni][2] * sc.z + sh.z, 0.f);
        float h3 = fmaxf(acc[ni][3] * sc.w + sh.w, 0.f);
        uint2 o;
        o.x = (unsigned)f2bf(h0) | ((unsigned)f2bf(h1) << 16);
        o.y = (unsigned)f2bf(h2) | ((unsigned)f2bf(h3) << 16);
        *(uint2*)((char*)sAd + (((lr << 4) + (g ^ (lr & 7))) << 4) + sub) = o;
    }
    __syncthreads();

    // MFMA2: [Q|R] = H @ W2T2^T ; wave w -> cols [32w, 32w+32)
    f32x4 acc2[2];
    acc2[0] = (f32x4){0.f, 0.f, 0.f, 0.f};
    acc2[1] = (f32x4){0.f, 0.f, 0.f, 0.f};

    #pragma unroll
    for (int kk = 0; kk < 4; ++kk) {
        bf16x8 a = *(const bf16x8*)((const char*)sAd +
                                    (((lr << 4) + ((kk * 4 + lk) ^ (lr & 7))) << 4));
        #pragma unroll
        for (int ni = 0; ni < 2; ++ni) {
            int c = wc + ni * 16 + lr;
            bf16x8 b = *(const bf16x8*)(W2T2 + (size_t)c * 128 + kk * 32 + lk * 8);
            acc2[ni] = __builtin_amdgcn_mfma_f32_16x16x32_bf16(b, a, acc2[ni], 0, 0, 0);
        }
    }

    const int rowo = row0 + lr;
    if (rowo < N_NODES) {
        #pragma unroll
        for (int ni = 0; ni < 2; ++ni) {
            int cw = wc + ni * 16 + lk * 4;
            if (cw < 64) {
                ushort4 o;
                o.x = f2bf(acc2[ni][0]); o.y = f2bf(acc2[ni][1]);
                o.z = f2bf(acc2[ni][2]); o.w = f2bf(acc2[ni][3]);
                *(ushort4*)(Q + ((size_t)rowo << 6) + cw) = o;
            } else {
                int c0 = cw - 64;
                float4 bias = *(const float4*)(b2 + c0);
                float4 o;
                o.x = acc2[ni][0] + bias.x; o.y = acc2[ni][1] + bias.y;
                o.z = acc2[ni][2] + bias.z; o.w = acc2[ni][3] + bias.w;
                *(float4*)(R + ((size_t)rowo << 6) + c0) = o;
            }
        }
    }
}

// ===========================================================================
// finish: out[n] = mean_j Q[j] + R[n].  Quarter-bucket scan (R10 loop form).
// ===========================================================================
__global__ __launch_bounds__(256) void finish_kernel(
    const ushort* __restrict__ Q, const float* __restrict__ R,
    const unsigned* __restrict__ bucket, const int* __restrict__ bcnt,
    float* __restrict__ out) {
    __shared__ ushort lell[16 * ELL_MAX];   // 2 KB
    __shared__ int lcnt[16];
    const int tid = threadIdx.x;
    const int bkt = blockIdx.x >> 2, q = blockIdx.x & 3;

    if (tid < 16) lcnt[tid] = 0;
    int n = bcnt[bkt];
    if (n > BUCKET_CAP) n = BUCKET_CAP;
    __syncthreads();
    for (int i = tid; i < n; i += 256) {
        unsigned u = bucket[(size_t)bkt * BUCKET_CAP + i];
        int dl = u & 63;
        if ((dl >> 4) == q) {
            int r = dl & 15;
            int p = atomicAdd(&lcnt[r], 1);
            if (p < ELL_MAX) lell[(r << 6) + p] = (ushort)(u >> 6);
        }
    }
    __syncthreads();

    const int grp = tid >> 4, lane16 = tid & 15;
    const int node = (bkt << 6) + (q << 4) + grp;
    if (node >= N_NODES) return;
    const int dg = lcnt[grp];
    const int end = dg < ELL_MAX ? dg : ELL_MAX;
    const ushort* Lp = lell + (grp << 6);
    float a0 = 0.f, a1 = 0.f, a2 = 0.f, a3 = 0.f;
    int j = 0;
    for (; j + 8 <= end; j += 8) {
        ushort4 sa = *(const ushort4*)(Lp + j);
        ushort4 sb = *(const ushort4*)(Lp + j + 4);
        uint2 u0 = *(const uint2*)(Q + ((size_t)sa.x << 6) + lane16 * 4);
        uint2 u1 = *(const uint2*)(Q + ((size_t)sa.y << 6) + lane16 * 4);
        uint2 u2 = *(const uint2*)(Q + ((size_t)sa.z << 6) + lane16 * 4);
        uint2 u3 = *(const uint2*)(Q + ((size_t)sa.w << 6) + lane16 * 4);
        uint2 u4 = *(const uint2*)(Q + ((size_t)sb.x << 6) + lane16 * 4);
        uint2 u5 = *(const uint2*)(Q + ((size_t)sb.y << 6) + lane16 * 4);
        uint2 u6 = *(const uint2*)(Q + ((size_t)sb.z << 6) + lane16 * 4);
        uint2 u7 = *(const uint2*)(Q + ((size_t)sb.w << 6) + lane16 * 4);
        a0 += bf_lo(u0.x) + bf_lo(u1.x) + bf_lo(u2.x) + bf_lo(u3.x)
            + bf_lo(u4.x) + bf_lo(u5.x) + bf_lo(u6.x) + bf_lo(u7.x);
        a1 += bf_hi(u0.x) + bf_hi(u1.x) + bf_hi(u2.x) + bf_hi(u3.x)
            + bf_hi(u4.x) + bf_hi(u5.x) + bf_hi(u6.x) + bf_hi(u7.x);
        a2 += bf_lo(u0.y) + bf_lo(u1.y) + bf_lo(u2.y) + bf_lo(u3.y)
            + bf_lo(u4.y) + bf_lo(u5.y) + bf_lo(u6.y) + bf_lo(u7.y);
        a3 += bf_hi(u0.y) + bf_hi(u1.y) + bf_hi(u2.y) + bf_hi(u3.y)
            + bf_hi(u4.y) + bf_hi(u5.y) + bf_hi(u6.y) + bf_hi(u7.y);
    }
    for (; j + 4 <= end; j += 4) {
        ushort4 ss = *(const ushort4*)(Lp + j);
        uint2 u0 = *(const uint2*)(Q + ((size_t)ss.x << 6) + lane16 * 4);
        uint2 u1 = *(const uint2*)(Q + ((size_t)ss.y << 6) + lane16 * 4);
        uint2 u2 = *(const uint2*)(Q + ((size_t)ss.z << 6) + lane16 * 4);
        uint2 u3 = *(const uint2*)(Q + ((size_t)ss.w << 6) + lane16 * 4);
        a0 += bf_lo(u0.x) + bf_lo(u1.x) + bf_lo(u2.x) + bf_lo(u3.x);
        a1 += bf_hi(u0.x) + bf_hi(u1.x) + bf_hi(u2.x) + bf_hi(u3.x);
        a2 += bf_lo(u0.y) + bf_lo(u1.y) + bf_lo(u2.y) + bf_lo(u3.y);
        a3 += bf_hi(u0.y) + bf_hi(u1.y) + bf_hi(u2.y) + bf_hi(u3.y);
    }
    for (; j < end; ++j) {
        int s = Lp[j];
        uint2 u = *(const uint2*)(Q + ((size_t)s << 6) + lane16 * 4);
        a0 += bf_lo(u.x); a1 += bf_hi(u.x);
        a2 += bf_lo(u.y); a3 += bf_hi(u.y);
    }
    float ic = 1.0f / fmaxf((float)dg, 1.0f);
    float4 r4 = *(const float4*)(R + ((size_t)node << 6) + lane16 * 4);
    float4 o;
    o.x = a0 * ic + r4.x;
    o.y = a1 * ic + r4.y;
    o.z = a2 * ic + r4.z;
    o.w = a3 * ic + r4.w;
    *(float4*)(out + ((size_t)node << 6) + lane16 * 4) = o;
}

// ---------------------------------------------------------------------------
extern "C" void kernel_launch(void* const* d_in, const int* in_sizes, int n_in,
                              void* d_out, int out_size, void* d_ws, size_t ws_size,
                              hipStream_t stream) {
    const float* x     = (const float*)d_in[0];
    const int*   eidx  = (const int*)d_in[1];
    const float* W1_l  = (const float*)d_in[2];
    const float* W1_r  = (const float*)d_in[3];
    const float* b1    = (const float*)d_in[4];
    const float* gamma = (const float*)d_in[5];
    const float* beta  = (const float*)d_in[6];
    const float* mean  = (const float*)d_in[7];
    const float* var   = (const float*)d_in[8];
    const float* W2_l  = (const float*)d_in[9];
    const float* W2_r  = (const float*)d_in[10];
    const float* b2    = (const float*)d_in[11];
    float* out = (float*)d_out;

    char* p = (char*)d_ws;
    ushort* Xb   = (ushort*)p; p += (size_t)N_NODES * 128 * 2;            // 12.8 MB
    ushort* Agg  = (ushort*)p; p += (size_t)N_NODES * 128 * 2;            // 12.8 MB
    ushort* Q    = (ushort*)p; p += (size_t)N_NODES * 64 * 2;             //  6.4 MB
    float*  R    = (float*)p;  p += (size_t)N_NODES * 64 * 4;             // 12.8 MB
    ushort* W1T  = (ushort*)p; p += 128 * 256 * 2;
    ushort* W2T2 = (ushort*)p; p += 128 * 128 * 2;
    float* scale_ = (float*)p; p += 128 * 4;
    float* shift_ = (float*)p; p += 128 * 4;
    unsigned* bucket = (unsigned*)p; p += (size_t)N_BUCKETS * BUCKET_CAP * 4; // 3.2 MB
    int* bcnt    = (int*)p;    p += (size_t)N_BUCKETS * 4;                // 3.1 KB

    zero_bcnt_kernel<<<(N_BUCKETS + 255) / 256, 256, 0, stream>>>(bcnt);

    prep_scatter_kernel<<<PREP_GRID, 256, 0, stream>>>(
        x, eidx, W1_l, W1_r, W2_l, W2_r, gamma, beta, mean, var, b1,
        Xb, W1T, W2T2, scale_, shift_, bcnt, bucket);

    gather1_kernel<<<N_BUCKETS * 4, 256, 0, stream>>>(Xb, bucket, bcnt, Agg);

    mm_kernel<<<(N_NODES + 15) / 16, 256, 0, stream>>>(
        Agg, Xb, W1T, W2T2, scale_, shift_, b2, Q, R);

    finish_kernel<<<N_BUCKETS * 4, 256, 0, stream>>>(Q, R, bucket, bcnt, out);
}

// Round 13
// 106.457 us; speedup vs baseline: 1.0482x; 1.0482x over previous
//
#include <hip/hip_runtime.h>
#include <hip/hip_bf16.h>

#define N_NODES 50000
#define N_EDGES 600000
#define BN_EPS 1e-5f
#define ELL_MAX 64          // per-node list cap; P(deg>=64) ~ 1e-30
#define N_BUCKETS 782       // ceil(50000/64) 64-node tiles
#define BUCKET_CAP 1024     // lambda=768, sigma=27.7 -> +9.2 sigma

#define EPT 8               // edges per thread in the binning blocks
#define EB_EDGES (256 * EPT)                    // 2048
#define N_EB ((N_EDGES + EB_EDGES - 1) / EB_EDGES)   // 293
#define N_CONV_BLK 6250                         // 1.6M threads / 256
#define N_W_BLK 192                             // 49152 / 256
#define PREP_GRID (N_EB + N_CONV_BLK + N_W_BLK + 1)

typedef short bf16x8 __attribute__((ext_vector_type(8)));
typedef float f32x4 __attribute__((ext_vector_type(4)));

__device__ __forceinline__ ushort f2bf(float f) {
    unsigned u = __float_as_uint(f);
    u += 0x7fffu + ((u >> 16) & 1u);
    return (ushort)(u >> 16);
}
__device__ __forceinline__ float bf_lo(unsigned u) { return __uint_as_float(u << 16); }
__device__ __forceinline__ float bf_hi(unsigned u) { return __uint_as_float(u & 0xffff0000u); }

// ===========================================================================
// zero_bcnt: hand-rolled (runtime tiny-fill path avoided).
// ===========================================================================
__global__ __launch_bounds__(256) void zero_bcnt_kernel(int* __restrict__ bcnt) {
    int t = blockIdx.x * 256 + threadIdx.x;
    if (t < N_BUCKETS) bcnt[t] = 0;
}

// ===========================================================================
// prep_scatter (block-range partitioned):
//   blocks [0, N_EB): LDS-aggregated edge binning, 2048 edges/block.
//   blocks [N_EB, +6250): x -> bf16 (Xb).
//   blocks [.., +192): weight transpose W1T / W2T2.
//   last block: bn fold.
// ===========================================================================
__global__ __launch_bounds__(256) void prep_scatter_kernel(
    const float* __restrict__ x, const int* __restrict__ eidx,
    const float* __restrict__ W1l, const float* __restrict__ W1r,
    const float* __restrict__ W2l, const float* __restrict__ W2r,
    const float* __restrict__ gamma, const float* __restrict__ beta,
    const float* __restrict__ mean, const float* __restrict__ var,
    const float* __restrict__ b1,
    ushort* __restrict__ Xb, ushort* __restrict__ W1T, ushort* __restrict__ W2T2,
    float* __restrict__ scale_, float* __restrict__ shift_,
    int* __restrict__ bcnt, unsigned* __restrict__ bucket) {
    const int blk = blockIdx.x;
    const int tid = threadIdx.x;

    if (blk < N_EB) {
        __shared__ int lcnt[N_BUCKETS];
        __shared__ int lbase[N_BUCKETS];
        const int e0 = blk * EB_EDGES;
        const int n = (N_EDGES - e0) < EB_EDGES ? (N_EDGES - e0) : EB_EDGES;

        for (int i = tid; i < N_BUCKETS; i += 256) lcnt[i] = 0;
        __syncthreads();

        // E1: histogram + rank; keep pk and packed src in registers
        unsigned pk[EPT];
        unsigned sp[EPT / 2];
        #pragma unroll
        for (int i = 0; i < EPT; ++i) {
            int idx = i * 256 + tid;
            if (idx < n) {
                int src = eidx[e0 + idx];
                int dst = eidx[N_EDGES + e0 + idx];
                int b = dst >> 6;
                int r = atomicAdd(&lcnt[b], 1);
                pk[i] = ((unsigned)b << 17) | ((unsigned)r << 6) | (unsigned)(dst & 63);
                if (i & 1) sp[i >> 1] |= ((unsigned)src << 16);
                else       sp[i >> 1]  = (unsigned)src & 0xFFFFu;
            } else {
                pk[i] = 0xFFFFFFFFu;
            }
        }
        __syncthreads();

        // E2: one global atomic per non-empty bin
        for (int i = tid; i < N_BUCKETS; i += 256) {
            int c = lcnt[i];
            lbase[i] = c ? atomicAdd(&bcnt[i], c) : 0;
        }
        __syncthreads();

        // E3: grouped scatter from registers
        #pragma unroll
        for (int i = 0; i < EPT; ++i) {
            if (pk[i] != 0xFFFFFFFFu) {
                int b = pk[i] >> 17;
                int r = (pk[i] >> 6) & 0x7FF;
                int dl = pk[i] & 63;
                unsigned src = (i & 1) ? (sp[i >> 1] >> 16) : (sp[i >> 1] & 0xFFFFu);
                int p = lbase[b] + r;
                if (p < BUCKET_CAP)
                    bucket[(size_t)b * BUCKET_CAP + p] = (src << 6) | (unsigned)dl;
            }
        }
    } else if (blk < N_EB + N_CONV_BLK) {
        int t = (blk - N_EB) * 256 + tid;           // < 1,600,000
        int row = t >> 5, c4 = t & 31;
        float4 v = *(const float4*)(x + (size_t)row * 128 + c4 * 4);
        ushort4 o;
        o.x = f2bf(v.x); o.y = f2bf(v.y); o.z = f2bf(v.z); o.w = f2bf(v.w);
        *(ushort4*)(Xb + (size_t)row * 128 + c4 * 4) = o;
    } else if (blk < N_EB + N_CONV_BLK + N_W_BLK) {
        int t2 = (blk - N_EB - N_CONV_BLK) * 256 + tid;   // < 49152
        if (t2 < 128 * 256) {
            int c = t2 >> 8, k = t2 & 255;
            float v = (k < 128) ? W1l[k * 128 + c] : W1r[(k - 128) * 128 + c];
            W1T[c * 256 + k] = f2bf(v);
        } else {
            int t3 = t2 - 128 * 256;            // 0..16383
            int c = t3 >> 7, k = t3 & 127;
            float v = (c < 64) ? W2l[k * 64 + c] : W2r[k * 64 + (c - 64)];
            W2T2[c * 128 + k] = f2bf(v);
        }
    } else {
        if (tid < 128) {
            int c = tid;
            float sc = gamma[c] * rsqrtf(var[c] + BN_EPS);
            scale_[c] = sc;
            shift_[c] = sc * (b1[c] - mean[c]) + beta[c];
        }
    }
}

// ===========================================================================
// gather1: one block per QUARTER-bucket (16 nodes). Scan the bucket's list
// into a 2KB LDS 16-node list, then gather-mean from Xb (R10 loop form).
// ===========================================================================
__global__ __launch_bounds__(256) void gather1_kernel(
    const ushort* __restrict__ Xb, const unsigned* __restrict__ bucket,
    const int* __restrict__ bcnt, ushort* __restrict__ Agg) {
    __shared__ ushort lell[16 * ELL_MAX];   // 2 KB
    __shared__ int lcnt[16];
    const int tid = threadIdx.x;
    const int bkt = blockIdx.x >> 2, q = blockIdx.x & 3;

    if (tid < 16) lcnt[tid] = 0;
    int n = bcnt[bkt];
    if (n > BUCKET_CAP) n = BUCKET_CAP;
    __syncthreads();
    for (int i = tid; i < n; i += 256) {
        unsigned u = bucket[(size_t)bkt * BUCKET_CAP + i];
        int dl = u & 63;
        if ((dl >> 4) == q) {
            int r = dl & 15;
            int p = atomicAdd(&lcnt[r], 1);
            if (p < ELL_MAX) lell[(r << 6) + p] = (ushort)(u >> 6);
        }
    }
    __syncthreads();

    const int grp = tid >> 4, lane16 = tid & 15;
    const int node = (bkt << 6) + (q << 4) + grp;
    if (node >= N_NODES) return;
    const int dg = lcnt[grp];
    const int end = dg < ELL_MAX ? dg : ELL_MAX;
    const ushort* Lp = lell + (grp << 6);
    float a0 = 0.f, a1 = 0.f, a2 = 0.f, a3 = 0.f;
    float a4 = 0.f, a5 = 0.f, a6 = 0.f, a7 = 0.f;
    int j = 0;
    for (; j + 8 <= end; j += 8) {
        ushort4 sa = *(const ushort4*)(Lp + j);
        ushort4 sb = *(const ushort4*)(Lp + j + 4);
        uint4 u0 = *(const uint4*)(Xb + ((size_t)sa.x << 7) + lane16 * 8);
        uint4 u1 = *(const uint4*)(Xb + ((size_t)sa.y << 7) + lane16 * 8);
        uint4 u2 = *(const uint4*)(Xb + ((size_t)sa.z << 7) + lane16 * 8);
        uint4 u3 = *(const uint4*)(Xb + ((size_t)sa.w << 7) + lane16 * 8);
        uint4 u4 = *(const uint4*)(Xb + ((size_t)sb.x << 7) + lane16 * 8);
        uint4 u5 = *(const uint4*)(Xb + ((size_t)sb.y << 7) + lane16 * 8);
        uint4 u6 = *(const uint4*)(Xb + ((size_t)sb.z << 7) + lane16 * 8);
        uint4 u7 = *(const uint4*)(Xb + ((size_t)sb.w << 7) + lane16 * 8);
        a0 += bf_lo(u0.x) + bf_lo(u1.x) + bf_lo(u2.x) + bf_lo(u3.x)
            + bf_lo(u4.x) + bf_lo(u5.x) + bf_lo(u6.x) + bf_lo(u7.x);
        a1 += bf_hi(u0.x) + bf_hi(u1.x) + bf_hi(u2.x) + bf_hi(u3.x)
            + bf_hi(u4.x) + bf_hi(u5.x) + bf_hi(u6.x) + bf_hi(u7.x);
        a2 += bf_lo(u0.y) + bf_lo(u1.y) + bf_lo(u2.y) + bf_lo(u3.y)
            + bf_lo(u4.y) + bf_lo(u5.y) + bf_lo(u6.y) + bf_lo(u7.y);
        a3 += bf_hi(u0.y) + bf_hi(u1.y) + bf_hi(u2.y) + bf_hi(u3.y)
            + bf_hi(u4.y) + bf_hi(u5.y) + bf_hi(u6.y) + bf_hi(u7.y);
        a4 += bf_lo(u0.z) + bf_lo(u1.z) + bf_lo(u2.z) + bf_lo(u3.z)
            + bf_lo(u4.z) + bf_lo(u5.z) + bf_lo(u6.z) + bf_lo(u7.z);
        a5 += bf_hi(u0.z) + bf_hi(u1.z) + bf_hi(u2.z) + bf_hi(u3.z)
            + bf_hi(u4.z) + bf_hi(u5.z) + bf_hi(u6.z) + bf_hi(u7.z);
        a6 += bf_lo(u0.w) + bf_lo(u1.w) + bf_lo(u2.w) + bf_lo(u3.w)
            + bf_lo(u4.w) + bf_lo(u5.w) + bf_lo(u6.w) + bf_lo(u7.w);
        a7 += bf_hi(u0.w) + bf_hi(u1.w) + bf_hi(u2.w) + bf_hi(u3.w)
            + bf_hi(u4.w) + bf_hi(u5.w) + bf_hi(u6.w) + bf_hi(u7.w);
    }
    for (; j + 4 <= end; j += 4) {
        ushort4 sa = *(const ushort4*)(Lp + j);
        uint4 u0 = *(const uint4*)(Xb + ((size_t)sa.x << 7) + lane16 * 8);
        uint4 u1 = *(const uint4*)(Xb + ((size_t)sa.y << 7) + lane16 * 8);
        uint4 u2 = *(const uint4*)(Xb + ((size_t)sa.z << 7) + lane16 * 8);
        uint4 u3 = *(const uint4*)(Xb + ((size_t)sa.w << 7) + lane16 * 8);
        a0 += bf_lo(u0.x) + bf_lo(u1.x) + bf_lo(u2.x) + bf_lo(u3.x);
        a1 += bf_hi(u0.x) + bf_hi(u1.x) + bf_hi(u2.x) + bf_hi(u3.x);
        a2 += bf_lo(u0.y) + bf_lo(u1.y) + bf_lo(u2.y) + bf_lo(u3.y);
        a3 += bf_hi(u0.y) + bf_hi(u1.y) + bf_hi(u2.y) + bf_hi(u3.y);
        a4 += bf_lo(u0.z) + bf_lo(u1.z) + bf_lo(u2.z) + bf_lo(u3.z);
        a5 += bf_hi(u0.z) + bf_hi(u1.z) + bf_hi(u2.z) + bf_hi(u3.z);
        a6 += bf_lo(u0.w) + bf_lo(u1.w) + bf_lo(u2.w) + bf_lo(u3.w);
        a7 += bf_hi(u0.w) + bf_hi(u1.w) + bf_hi(u2.w) + bf_hi(u3.w);
    }
    for (; j < end; ++j) {
        int s = Lp[j];
        uint4 u = *(const uint4*)(Xb + ((size_t)s << 7) + lane16 * 8);
        a0 += bf_lo(u.x); a1 += bf_hi(u.x);
        a2 += bf_lo(u.y); a3 += bf_hi(u.y);
        a4 += bf_lo(u.z); a5 += bf_hi(u.z);
        a6 += bf_lo(u.w); a7 += bf_hi(u.w);
    }
    float ic = 1.0f / fmaxf((float)dg, 1.0f);
    uint4 o;
    o.x = (unsigned)f2bf(a0 * ic) | ((unsigned)f2bf(a1 * ic) << 16);
    o.y = (unsigned)f2bf(a2 * ic) | ((unsigned)f2bf(a3 * ic) << 16);
    o.z = (unsigned)f2bf(a4 * ic) | ((unsigned)f2bf(a5 * ic) << 16);
    o.w = (unsigned)f2bf(a6 * ic) | ((unsigned)f2bf(a7 * ic) << 16);
    *(uint4*)(Agg + ((size_t)node << 7) + lane16 * 8) = o;
}

// ===========================================================================
// mm: 16-row tiles, 3125 blocks x 256 thr (4 waves), 8KB LDS.
// R12 lesson: VGPR_Count=24 -> compiler serialized every W-load against its
// MFMA (24 dependent L2 round-trips/wave, MfmaUtil 3.4%). Fix: register-
// hoist ALL 24 weight fragments (96 VGPR) -- independent loads issued
// together right after the A-stage loads, ONE L2 round-trip that completes
// under the stage+barrier. MFMAs then run register-fed.
// ===========================================================================
__global__ __launch_bounds__(256) void mm_kernel(
    const ushort* __restrict__ Agg, const ushort* __restrict__ Xb,
    const ushort* __restrict__ W1T, const ushort* __restrict__ W2T2,
    const float* __restrict__ scale_, const float* __restrict__ shift_,
    const float* __restrict__ b2,
    ushort* __restrict__ Q, float* __restrict__ R) {
    __shared__ unsigned sAd[16 * 32 * 4];   // 8 KB
    const int tid = threadIdx.x;
    const int row0 = blockIdx.x * 16;
    const int w = tid >> 6, l = tid & 63;
    const int wc = w << 5;              // 0,32,64,96
    const int lr = l & 15, lk = l >> 4;

    // ---- issue A-stage loads first (they feed the barrier) ----
    uint4 sv[2];
    int sr[2], sg[2];
    #pragma unroll
    for (int i = 0; i < 2; ++i) {
        int g = i * 256 + tid;
        sr[i] = g >> 5; sg[i] = g & 31;
        int row = row0 + sr[i];
        sv[i] = make_uint4(0, 0, 0, 0);
        if (row < N_NODES) {
            const ushort* src = (sg[i] < 16)
                ? (Agg + ((size_t)row << 7) + sg[i] * 8)
                : (Xb + ((size_t)row << 7) + (sg[i] - 16) * 8);
            sv[i] = *(const uint4*)src;
        }
    }

    // ---- prefetch ALL weight fragments (independent; overlap into one
    //      L2 round-trip that hides under the stage/barrier) ----
    bf16x8 bw1[8][2];
    #pragma unroll
    for (int kk = 0; kk < 8; ++kk)
        #pragma unroll
        for (int ni = 0; ni < 2; ++ni)
            bw1[kk][ni] = *(const bf16x8*)(W1T +
                (size_t)(wc + ni * 16 + lr) * 256 + kk * 32 + lk * 8);
    bf16x8 bw2[4][2];
    #pragma unroll
    for (int kk = 0; kk < 4; ++kk)
        #pragma unroll
        for (int ni = 0; ni < 2; ++ni)
            bw2[kk][ni] = *(const bf16x8*)(W2T2 +
                (size_t)(wc + ni * 16 + lr) * 128 + kk * 32 + lk * 8);

    // ---- LDS write of staged A, then barrier ----
    #pragma unroll
    for (int i = 0; i < 2; ++i)
        *(uint4*)&sAd[((sr[i] << 5) + (sg[i] ^ (sr[i] & 7))) << 2] = sv[i];
    __syncthreads();

    const bf16x8* sA8 = (const bf16x8*)sAd;

    f32x4 acc[2];
    acc[0] = (f32x4){0.f, 0.f, 0.f, 0.f};
    acc[1] = (f32x4){0.f, 0.f, 0.f, 0.f};

    #pragma unroll
    for (int kk = 0; kk < 8; ++kk) {
        bf16x8 a = sA8[(lr << 5) + ((kk * 4 + lk) ^ (lr & 7))];
        acc[0] = __builtin_amdgcn_mfma_f32_16x16x32_bf16(bw1[kk][0], a, acc[0], 0, 0, 0);
        acc[1] = __builtin_amdgcn_mfma_f32_16x16x32_bf16(bw1[kk][1], a, acc[1], 0, 0, 0);
    }
    __syncthreads();   // all sA reads done before H overwrites low 4KB

    // bn+relu, H (bf16) -> sH = sAd[0..4KB), [16 r][16 g] swizzled
    #pragma unroll
    for (int ni = 0; ni < 2; ++ni) {
        int c0 = wc + ni * 16 + lk * 4;
        float4 sc = *(const float4*)(scale_ + c0);
        float4 sh = *(const float4*)(shift_ + c0);
        int g = c0 >> 3;
        int sub = (c0 & 4) ? 8 : 0;
        float h0 = fmaxf(acc[ni][0] * sc.x + sh.x, 0.f);
        float h1 = fmaxf(acc[ni][1] * sc.y + sh.y, 0.f);
        float h2 = fmaxf(acc[ni][2] * sc.z + sh.z, 0.f);
        float h3 = fmaxf(acc[ni][3] * sc.w + sh.w, 0.f);
        uint2 o;
        o.x = (unsigned)f2bf(h0) | ((unsigned)f2bf(h1) << 16);
        o.y = (unsigned)f2bf(h2) | ((unsigned)f2bf(h3) << 16);
        *(uint2*)((char*)sAd + (((lr << 4) + (g ^ (lr & 7))) << 4) + sub) = o;
    }
    __syncthreads();

    // MFMA2: [Q|R] = H @ W2T2^T ; wave w -> cols [32w, 32w+32)
    f32x4 acc2[2];
    acc2[0] = (f32x4){0.f, 0.f, 0.f, 0.f};
    acc2[1] = (f32x4){0.f, 0.f, 0.f, 0.f};

    #pragma unroll
    for (int kk = 0; kk < 4; ++kk) {
        bf16x8 a = *(const bf16x8*)((const char*)sAd +
                                    (((lr << 4) + ((kk * 4 + lk) ^ (lr & 7))) << 4));
        acc2[0] = __builtin_amdgcn_mfma_f32_16x16x32_bf16(bw2[kk][0], a, acc2[0], 0, 0, 0);
        acc2[1] = __builtin_amdgcn_mfma_f32_16x16x32_bf16(bw2[kk][1], a, acc2[1], 0, 0, 0);
    }

    const int rowo = row0 + lr;
    if (rowo < N_NODES) {
        #pragma unroll
        for (int ni = 0; ni < 2; ++ni) {
            int cw = wc + ni * 16 + lk * 4;
            if (cw < 64) {
                ushort4 o;
                o.x = f2bf(acc2[ni][0]); o.y = f2bf(acc2[ni][1]);
                o.z = f2bf(acc2[ni][2]); o.w = f2bf(acc2[ni][3]);
                *(ushort4*)(Q + ((size_t)rowo << 6) + cw) = o;
            } else {
                int c0 = cw - 64;
                float4 bias = *(const float4*)(b2 + c0);
                float4 o;
                o.x = acc2[ni][0] + bias.x; o.y = acc2[ni][1] + bias.y;
                o.z = acc2[ni][2] + bias.z; o.w = acc2[ni][3] + bias.w;
                *(float4*)(R + ((size_t)rowo << 6) + c0) = o;
            }
        }
    }
}

// ===========================================================================
// finish: out[n] = mean_j Q[j] + R[n].  Quarter-bucket scan (R10 loop form).
// ===========================================================================
__global__ __launch_bounds__(256) void finish_kernel(
    const ushort* __restrict__ Q, const float* __restrict__ R,
    const unsigned* __restrict__ bucket, const int* __restrict__ bcnt,
    float* __restrict__ out) {
    __shared__ ushort lell[16 * ELL_MAX];   // 2 KB
    __shared__ int lcnt[16];
    const int tid = threadIdx.x;
    const int bkt = blockIdx.x >> 2, q = blockIdx.x & 3;

    if (tid < 16) lcnt[tid] = 0;
    int n = bcnt[bkt];
    if (n > BUCKET_CAP) n = BUCKET_CAP;
    __syncthreads();
    for (int i = tid; i < n; i += 256) {
        unsigned u = bucket[(size_t)bkt * BUCKET_CAP + i];
        int dl = u & 63;
        if ((dl >> 4) == q) {
            int r = dl & 15;
            int p = atomicAdd(&lcnt[r], 1);
            if (p < ELL_MAX) lell[(r << 6) + p] = (ushort)(u >> 6);
        }
    }
    __syncthreads();

    const int grp = tid >> 4, lane16 = tid & 15;
    const int node = (bkt << 6) + (q << 4) + grp;
    if (node >= N_NODES) return;
    const int dg = lcnt[grp];
    const int end = dg < ELL_MAX ? dg : ELL_MAX;
    const ushort* Lp = lell + (grp << 6);
    float a0 = 0.f, a1 = 0.f, a2 = 0.f, a3 = 0.f;
    int j = 0;
    for (; j + 8 <= end; j += 8) {
        ushort4 sa = *(const ushort4*)(Lp + j);
        ushort4 sb = *(const ushort4*)(Lp + j + 4);
        uint2 u0 = *(const uint2*)(Q + ((size_t)sa.x << 6) + lane16 * 4);
        uint2 u1 = *(const uint2*)(Q + ((size_t)sa.y << 6) + lane16 * 4);
        uint2 u2 = *(const uint2*)(Q + ((size_t)sa.z << 6) + lane16 * 4);
        uint2 u3 = *(const uint2*)(Q + ((size_t)sa.w << 6) + lane16 * 4);
        uint2 u4 = *(const uint2*)(Q + ((size_t)sb.x << 6) + lane16 * 4);
        uint2 u5 = *(const uint2*)(Q + ((size_t)sb.y << 6) + lane16 * 4);
        uint2 u6 = *(const uint2*)(Q + ((size_t)sb.z << 6) + lane16 * 4);
        uint2 u7 = *(const uint2*)(Q + ((size_t)sb.w << 6) + lane16 * 4);
        a0 += bf_lo(u0.x) + bf_lo(u1.x) + bf_lo(u2.x) + bf_lo(u3.x)
            + bf_lo(u4.x) + bf_lo(u5.x) + bf_lo(u6.x) + bf_lo(u7.x);
        a1 += bf_hi(u0.x) + bf_hi(u1.x) + bf_hi(u2.x) + bf_hi(u3.x)
            + bf_hi(u4.x) + bf_hi(u5.x) + bf_hi(u6.x) + bf_hi(u7.x);
        a2 += bf_lo(u0.y) + bf_lo(u1.y) + bf_lo(u2.y) + bf_lo(u3.y)
            + bf_lo(u4.y) + bf_lo(u5.y) + bf_lo(u6.y) + bf_lo(u7.y);
        a3 += bf_hi(u0.y) + bf_hi(u1.y) + bf_hi(u2.y) + bf_hi(u3.y)
            + bf_hi(u4.y) + bf_hi(u5.y) + bf_hi(u6.y) + bf_hi(u7.y);
    }
    for (; j + 4 <= end; j += 4) {
        ushort4 ss = *(const ushort4*)(Lp + j);
        uint2 u0 = *(const uint2*)(Q + ((size_t)ss.x << 6) + lane16 * 4);
        uint2 u1 = *(const uint2*)(Q + ((size_t)ss.y << 6) + lane16 * 4);
        uint2 u2 = *(const uint2*)(Q + ((size_t)ss.z << 6) + lane16 * 4);
        uint2 u3 = *(const uint2*)(Q + ((size_t)ss.w << 6) + lane16 * 4);
        a0 += bf_lo(u0.x) + bf_lo(u1.x) + bf_lo(u2.x) + bf_lo(u3.x);
        a1 += bf_hi(u0.x) + bf_hi(u1.x) + bf_hi(u2.x) + bf_hi(u3.x);
        a2 += bf_lo(u0.y) + bf_lo(u1.y) + bf_lo(u2.y) + bf_lo(u3.y);
        a3 += bf_hi(u0.y) + bf_hi(u1.y) + bf_hi(u2.y) + bf_hi(u3.y);
    }
    for (; j < end; ++j) {
        int s = Lp[j];
        uint2 u = *(const uint2*)(Q + ((size_t)s << 6) + lane16 * 4);
        a0 += bf_lo(u.x); a1 += bf_hi(u.x);
        a2 += bf_lo(u.y); a3 += bf_hi(u.y);
    }
    float ic = 1.0f / fmaxf((float)dg, 1.0f);
    float4 r4 = *(const float4*)(R + ((size_t)node << 6) + lane16 * 4);
    float4 o;
    o.x = a0 * ic + r4.x;
    o.y = a1 * ic + r4.y;
    o.z = a2 * ic + r4.z;
    o.w = a3 * ic + r4.w;
    *(float4*)(out + ((size_t)node << 6) + lane16 * 4) = o;
}

// ---------------------------------------------------------------------------
extern "C" void kernel_launch(void* const* d_in, const int* in_sizes, int n_in,
                              void* d_out, int out_size, void* d_ws, size_t ws_size,
                              hipStream_t stream) {
    const float* x     = (const float*)d_in[0];
    const int*   eidx  = (const int*)d_in[1];
    const float* W1_l  = (const float*)d_in[2];
    const float* W1_r  = (const float*)d_in[3];
    const float* b1    = (const float*)d_in[4];
    const float* gamma = (const float*)d_in[5];
    const float* beta  = (const float*)d_in[6];
    const float* mean  = (const float*)d_in[7];
    const float* var   = (const float*)d_in[8];
    const float* W2_l  = (const float*)d_in[9];
    const float* W2_r  = (const float*)d_in[10];
    const float* b2    = (const float*)d_in[11];
    float* out = (float*)d_out;

    char* p = (char*)d_ws;
    ushort* Xb   = (ushort*)p; p += (size_t)N_NODES * 128 * 2;            // 12.8 MB
    ushort* Agg  = (ushort*)p; p += (size_t)N_NODES * 128 * 2;            // 12.8 MB
    ushort* Q    = (ushort*)p; p += (size_t)N_NODES * 64 * 2;             //  6.4 MB
    float*  R    = (float*)p;  p += (size_t)N_NODES * 64 * 4;             // 12.8 MB
    ushort* W1T  = (ushort*)p; p += 128 * 256 * 2;
    ushort* W2T2 = (ushort*)p; p += 128 * 128 * 2;
    float* scale_ = (float*)p; p += 128 * 4;
    float* shift_ = (float*)p; p += 128 * 4;
    unsigned* bucket = (unsigned*)p; p += (size_t)N_BUCKETS * BUCKET_CAP * 4; // 3.2 MB
    int* bcnt    = (int*)p;    p += (size_t)N_BUCKETS * 4;                // 3.1 KB

    zero_bcnt_kernel<<<(N_BUCKETS + 255) / 256, 256, 0, stream>>>(bcnt);

    prep_scatter_kernel<<<PREP_GRID, 256, 0, stream>>>(
        x, eidx, W1_l, W1_r, W2_l, W2_r, gamma, beta, mean, var, b1,
        Xb, W1T, W2T2, scale_, shift_, bcnt, bucket);

    gather1_kernel<<<N_BUCKETS * 4, 256, 0, stream>>>(Xb, bucket, bcnt, Agg);

    mm_kernel<<<(N_NODES + 15) / 16, 256, 0, stream>>>(
        Agg, Xb, W1T, W2T2, scale_, shift_, b2, Q, R);

    finish_kernel<<<N_BUCKETS * 4, 256, 0, stream>>>(Q, R, bucket, bcnt, out);
}

// Round 14
// 91.783 us; speedup vs baseline: 1.2157x; 1.1599x over previous
//
#include <hip/hip_runtime.h>
#include <hip/hip_bf16.h>

#define N_NODES 50000
#define N_EDGES 600000
#define BN_EPS 1e-5f
#define ELL_MAX 64          // per-node list cap; P(deg>=64) ~ 1e-30
#define N_BUCKETS 782       // ceil(50000/64) 64-node tiles
#define BUCKET_CAP 1024     // lambda=768, sigma=27.7 -> +9.2 sigma

#define EPT 8               // edges per thread in the binning blocks
#define EB_EDGES (256 * EPT)                    // 2048
#define N_EB ((N_EDGES + EB_EDGES - 1) / EB_EDGES)   // 293
#define N_CONV_BLK 6250                         // 1.6M threads / 256
#define N_W_BLK 192                             // 49152 / 256
#define PREP_GRID (N_EB + N_CONV_BLK + N_W_BLK + 1)

#define N_TILES 3125        // 50000 / 16
#define MM_GRID 1024        // 4 blocks/CU; each block ~3 tiles, weights loaded once

typedef short bf16x8 __attribute__((ext_vector_type(8)));
typedef float f32x4 __attribute__((ext_vector_type(4)));

__device__ __forceinline__ ushort f2bf(float f) {
    unsigned u = __float_as_uint(f);
    u += 0x7fffu + ((u >> 16) & 1u);
    return (ushort)(u >> 16);
}
__device__ __forceinline__ float bf_lo(unsigned u) { return __uint_as_float(u << 16); }
__device__ __forceinline__ float bf_hi(unsigned u) { return __uint_as_float(u & 0xffff0000u); }

// ===========================================================================
// zero_bcnt: hand-rolled (runtime tiny-fill path avoided).
// ===========================================================================
__global__ __launch_bounds__(256) void zero_bcnt_kernel(int* __restrict__ bcnt) {
    int t = blockIdx.x * 256 + threadIdx.x;
    if (t < N_BUCKETS) bcnt[t] = 0;
}

// ===========================================================================
// prep_scatter (block-range partitioned):
//   blocks [0, N_EB): LDS-aggregated edge binning, 2048 edges/block.
//   blocks [N_EB, +6250): x -> bf16 (Xb).
//   blocks [.., +192): weight transpose W1T / W2T2.
//   last block: bn fold.
// ===========================================================================
__global__ __launch_bounds__(256) void prep_scatter_kernel(
    const float* __restrict__ x, const int* __restrict__ eidx,
    const float* __restrict__ W1l, const float* __restrict__ W1r,
    const float* __restrict__ W2l, const float* __restrict__ W2r,
    const float* __restrict__ gamma, const float* __restrict__ beta,
    const float* __restrict__ mean, const float* __restrict__ var,
    const float* __restrict__ b1,
    ushort* __restrict__ Xb, ushort* __restrict__ W1T, ushort* __restrict__ W2T2,
    float* __restrict__ scale_, float* __restrict__ shift_,
    int* __restrict__ bcnt, unsigned* __restrict__ bucket) {
    const int blk = blockIdx.x;
    const int tid = threadIdx.x;

    if (blk < N_EB) {
        __shared__ int lcnt[N_BUCKETS];
        __shared__ int lbase[N_BUCKETS];
        const int e0 = blk * EB_EDGES;
        const int n = (N_EDGES - e0) < EB_EDGES ? (N_EDGES - e0) : EB_EDGES;

        for (int i = tid; i < N_BUCKETS; i += 256) lcnt[i] = 0;
        __syncthreads();

        // E1: histogram + rank; keep pk and packed src in registers
        unsigned pk[EPT];
        unsigned sp[EPT / 2];
        #pragma unroll
        for (int i = 0; i < EPT; ++i) {
            int idx = i * 256 + tid;
            if (idx < n) {
                int src = eidx[e0 + idx];
                int dst = eidx[N_EDGES + e0 + idx];
                int b = dst >> 6;
                int r = atomicAdd(&lcnt[b], 1);
                pk[i] = ((unsigned)b << 17) | ((unsigned)r << 6) | (unsigned)(dst & 63);
                if (i & 1) sp[i >> 1] |= ((unsigned)src << 16);
                else       sp[i >> 1]  = (unsigned)src & 0xFFFFu;
            } else {
                pk[i] = 0xFFFFFFFFu;
            }
        }
        __syncthreads();

        // E2: one global atomic per non-empty bin
        for (int i = tid; i < N_BUCKETS; i += 256) {
            int c = lcnt[i];
            lbase[i] = c ? atomicAdd(&bcnt[i], c) : 0;
        }
        __syncthreads();

        // E3: grouped scatter from registers
        #pragma unroll
        for (int i = 0; i < EPT; ++i) {
            if (pk[i] != 0xFFFFFFFFu) {
                int b = pk[i] >> 17;
                int r = (pk[i] >> 6) & 0x7FF;
                int dl = pk[i] & 63;
                unsigned src = (i & 1) ? (sp[i >> 1] >> 16) : (sp[i >> 1] & 0xFFFFu);
                int p = lbase[b] + r;
                if (p < BUCKET_CAP)
                    bucket[(size_t)b * BUCKET_CAP + p] = (src << 6) | (unsigned)dl;
            }
        }
    } else if (blk < N_EB + N_CONV_BLK) {
        int t = (blk - N_EB) * 256 + tid;           // < 1,600,000
        int row = t >> 5, c4 = t & 31;
        float4 v = *(const float4*)(x + (size_t)row * 128 + c4 * 4);
        ushort4 o;
        o.x = f2bf(v.x); o.y = f2bf(v.y); o.z = f2bf(v.z); o.w = f2bf(v.w);
        *(ushort4*)(Xb + (size_t)row * 128 + c4 * 4) = o;
    } else if (blk < N_EB + N_CONV_BLK + N_W_BLK) {
        int t2 = (blk - N_EB - N_CONV_BLK) * 256 + tid;   // < 49152
        if (t2 < 128 * 256) {
            int c = t2 >> 8, k = t2 & 255;
            float v = (k < 128) ? W1l[k * 128 + c] : W1r[(k - 128) * 128 + c];
            W1T[c * 256 + k] = f2bf(v);
        } else {
            int t3 = t2 - 128 * 256;            // 0..16383
            int c = t3 >> 7, k = t3 & 127;
            float v = (c < 64) ? W2l[k * 64 + c] : W2r[k * 64 + (c - 64)];
            W2T2[c * 128 + k] = f2bf(v);
        }
    } else {
        if (tid < 128) {
            int c = tid;
            float sc = gamma[c] * rsqrtf(var[c] + BN_EPS);
            scale_[c] = sc;
            shift_[c] = sc * (b1[c] - mean[c]) + beta[c];
        }
    }
}

// ===========================================================================
// gather1: one block per QUARTER-bucket (16 nodes). Scan the bucket's list
// into a 2KB LDS 16-node list, then gather-mean from Xb (R10 loop form).
// ===========================================================================
__global__ __launch_bounds__(256) void gather1_kernel(
    const ushort* __restrict__ Xb, const unsigned* __restrict__ bucket,
    const int* __restrict__ bcnt, ushort* __restrict__ Agg) {
    __shared__ ushort lell[16 * ELL_MAX];   // 2 KB
    __shared__ int lcnt[16];
    const int tid = threadIdx.x;
    const int bkt = blockIdx.x >> 2, q = blockIdx.x & 3;

    if (tid < 16) lcnt[tid] = 0;
    int n = bcnt[bkt];
    if (n > BUCKET_CAP) n = BUCKET_CAP;
    __syncthreads();
    for (int i = tid; i < n; i += 256) {
        unsigned u = bucket[(size_t)bkt * BUCKET_CAP + i];
        int dl = u & 63;
        if ((dl >> 4) == q) {
            int r = dl & 15;
            int p = atomicAdd(&lcnt[r], 1);
            if (p < ELL_MAX) lell[(r << 6) + p] = (ushort)(u >> 6);
        }
    }
    __syncthreads();

    const int grp = tid >> 4, lane16 = tid & 15;
    const int node = (bkt << 6) + (q << 4) + grp;
    if (node >= N_NODES) return;
    const int dg = lcnt[grp];
    const int end = dg < ELL_MAX ? dg : ELL_MAX;
    const ushort* Lp = lell + (grp << 6);
    float a0 = 0.f, a1 = 0.f, a2 = 0.f, a3 = 0.f;
    float a4 = 0.f, a5 = 0.f, a6 = 0.f, a7 = 0.f;
    int j = 0;
    for (; j + 8 <= end; j += 8) {
        ushort4 sa = *(const ushort4*)(Lp + j);
        ushort4 sb = *(const ushort4*)(Lp + j + 4);
        uint4 u0 = *(const uint4*)(Xb + ((size_t)sa.x << 7) + lane16 * 8);
        uint4 u1 = *(const uint4*)(Xb + ((size_t)sa.y << 7) + lane16 * 8);
        uint4 u2 = *(const uint4*)(Xb + ((size_t)sa.z << 7) + lane16 * 8);
        uint4 u3 = *(const uint4*)(Xb + ((size_t)sa.w << 7) + lane16 * 8);
        uint4 u4 = *(const uint4*)(Xb + ((size_t)sb.x << 7) + lane16 * 8);
        uint4 u5 = *(const uint4*)(Xb + ((size_t)sb.y << 7) + lane16 * 8);
        uint4 u6 = *(const uint4*)(Xb + ((size_t)sb.z << 7) + lane16 * 8);
        uint4 u7 = *(const uint4*)(Xb + ((size_t)sb.w << 7) + lane16 * 8);
        a0 += bf_lo(u0.x) + bf_lo(u1.x) + bf_lo(u2.x) + bf_lo(u3.x)
            + bf_lo(u4.x) + bf_lo(u5.x) + bf_lo(u6.x) + bf_lo(u7.x);
        a1 += bf_hi(u0.x) + bf_hi(u1.x) + bf_hi(u2.x) + bf_hi(u3.x)
            + bf_hi(u4.x) + bf_hi(u5.x) + bf_hi(u6.x) + bf_hi(u7.x);
        a2 += bf_lo(u0.y) + bf_lo(u1.y) + bf_lo(u2.y) + bf_lo(u3.y)
            + bf_lo(u4.y) + bf_lo(u5.y) + bf_lo(u6.y) + bf_lo(u7.y);
        a3 += bf_hi(u0.y) + bf_hi(u1.y) + bf_hi(u2.y) + bf_hi(u3.y)
            + bf_hi(u4.y) + bf_hi(u5.y) + bf_hi(u6.y) + bf_hi(u7.y);
        a4 += bf_lo(u0.z) + bf_lo(u1.z) + bf_lo(u2.z) + bf_lo(u3.z)
            + bf_lo(u4.z) + bf_lo(u5.z) + bf_lo(u6.z) + bf_lo(u7.z);
        a5 += bf_hi(u0.z) + bf_hi(u1.z) + bf_hi(u2.z) + bf_hi(u3.z)
            + bf_hi(u4.z) + bf_hi(u5.z) + bf_hi(u6.z) + bf_hi(u7.z);
        a6 += bf_lo(u0.w) + bf_lo(u1.w) + bf_lo(u2.w) + bf_lo(u3.w)
            + bf_lo(u4.w) + bf_lo(u5.w) + bf_lo(u6.w) + bf_lo(u7.w);
        a7 += bf_hi(u0.w) + bf_hi(u1.w) + bf_hi(u2.w) + bf_hi(u3.w)
            + bf_hi(u4.w) + bf_hi(u5.w) + bf_hi(u6.w) + bf_hi(u7.w);
    }
    for (; j + 4 <= end; j += 4) {
        ushort4 sa = *(const ushort4*)(Lp + j);
        uint4 u0 = *(const uint4*)(Xb + ((size_t)sa.x << 7) + lane16 * 8);
        uint4 u1 = *(const uint4*)(Xb + ((size_t)sa.y << 7) + lane16 * 8);
        uint4 u2 = *(const uint4*)(Xb + ((size_t)sa.z << 7) + lane16 * 8);
        uint4 u3 = *(const uint4*)(Xb + ((size_t)sa.w << 7) + lane16 * 8);
        a0 += bf_lo(u0.x) + bf_lo(u1.x) + bf_lo(u2.x) + bf_lo(u3.x);
        a1 += bf_hi(u0.x) + bf_hi(u1.x) + bf_hi(u2.x) + bf_hi(u3.x);
        a2 += bf_lo(u0.y) + bf_lo(u1.y) + bf_lo(u2.y) + bf_lo(u3.y);
        a3 += bf_hi(u0.y) + bf_hi(u1.y) + bf_hi(u2.y) + bf_hi(u3.y);
        a4 += bf_lo(u0.z) + bf_lo(u1.z) + bf_lo(u2.z) + bf_lo(u3.z);
        a5 += bf_hi(u0.z) + bf_hi(u1.z) + bf_hi(u2.z) + bf_hi(u3.z);
        a6 += bf_lo(u0.w) + bf_lo(u1.w) + bf_lo(u2.w) + bf_lo(u3.w);
        a7 += bf_hi(u0.w) + bf_hi(u1.w) + bf_hi(u2.w) + bf_hi(u3.w);
    }
    for (; j < end; ++j) {
        int s = Lp[j];
        uint4 u = *(const uint4*)(Xb + ((size_t)s << 7) + lane16 * 8);
        a0 += bf_lo(u.x); a1 += bf_hi(u.x);
        a2 += bf_lo(u.y); a3 += bf_hi(u.y);
        a4 += bf_lo(u.z); a5 += bf_hi(u.z);
        a6 += bf_lo(u.w); a7 += bf_hi(u.w);
    }
    float ic = 1.0f / fmaxf((float)dg, 1.0f);
    uint4 o;
    o.x = (unsigned)f2bf(a0 * ic) | ((unsigned)f2bf(a1 * ic) << 16);
    o.y = (unsigned)f2bf(a2 * ic) | ((unsigned)f2bf(a3 * ic) << 16);
    o.z = (unsigned)f2bf(a4 * ic) | ((unsigned)f2bf(a5 * ic) << 16);
    o.w = (unsigned)f2bf(a6 * ic) | ((unsigned)f2bf(a7 * ic) << 16);
    *(uint4*)(Agg + ((size_t)node << 7) + lane16 * 8) = o;
}

// ===========================================================================
// mm: GRID-STRIDE over 16-row tiles, 1024 blocks x 256 thr.
// R13 lesson: 3125 blocks each re-read the 96KB weight set (300MB of L3
// traffic ~ the whole 43us). Here each block loads its wave's 24 weight
// fragments ONCE (loop-invariant -> pinned in VGPRs) and processes ~3 tiles.
// Weight traffic 300 -> 98MB; inner loop is register-fed MFMA.
// ===========================================================================
__global__ __launch_bounds__(256) void mm_kernel(
    const ushort* __restrict__ Agg, const ushort* __restrict__ Xb,
    const ushort* __restrict__ W1T, const ushort* __restrict__ W2T2,
    const float* __restrict__ scale_, const float* __restrict__ shift_,
    const float* __restrict__ b2,
    ushort* __restrict__ Q, float* __restrict__ R) {
    __shared__ unsigned sAd[16 * 32 * 4];   // 8 KB
    const int tid = threadIdx.x;
    const int w = tid >> 6, l = tid & 63;
    const int wc = w << 5;              // 0,32,64,96
    const int lr = l & 15, lk = l >> 4;

    // ---- load all weight fragments ONCE (loop-invariant across tiles) ----
    bf16x8 bw1[8][2];
    #pragma unroll
    for (int kk = 0; kk < 8; ++kk)
        #pragma unroll
        for (int ni = 0; ni < 2; ++ni)
            bw1[kk][ni] = *(const bf16x8*)(W1T +
                (size_t)(wc + ni * 16 + lr) * 256 + kk * 32 + lk * 8);
    bf16x8 bw2[4][2];
    #pragma unroll
    for (int kk = 0; kk < 4; ++kk)
        #pragma unroll
        for (int ni = 0; ni < 2; ++ni)
            bw2[kk][ni] = *(const bf16x8*)(W2T2 +
                (size_t)(wc + ni * 16 + lr) * 128 + kk * 32 + lk * 8);

    // ---- bn params (also loop-invariant) ----
    float4 scv[2], shv[2];
    #pragma unroll
    for (int ni = 0; ni < 2; ++ni) {
        int c0 = wc + ni * 16 + lk * 4;
        scv[ni] = *(const float4*)(scale_ + c0);
        shv[ni] = *(const float4*)(shift_ + c0);
    }

    const bf16x8* sA8 = (const bf16x8*)sAd;
    const int sr = tid >> 4, sg0 = tid & 15;      // stage coords, iter 0
    const int sr1 = (256 + tid) >> 4 - 0;         // (unused; kept simple below)

    for (int t = blockIdx.x; t < N_TILES; t += MM_GRID) {
        const int row0 = t << 4;

        // stage: 512 granules over 256 threads (2 each)
        #pragma unroll
        for (int i = 0; i < 2; ++i) {
            int g = i * 256 + tid;
            int r = g >> 5, gx = g & 31;
            int row = row0 + r;
            uint4 v = make_uint4(0, 0, 0, 0);
            if (row < N_NODES) {
                const ushort* src = (gx < 16)
                    ? (Agg + ((size_t)row << 7) + gx * 8)
                    : (Xb + ((size_t)row << 7) + (gx - 16) * 8);
                v = *(const uint4*)src;
            }
            *(uint4*)&sAd[((r << 5) + (gx ^ (r & 7))) << 2] = v;
        }
        __syncthreads();

        f32x4 acc[2];
        acc[0] = (f32x4){0.f, 0.f, 0.f, 0.f};
        acc[1] = (f32x4){0.f, 0.f, 0.f, 0.f};

        #pragma unroll
        for (int kk = 0; kk < 8; ++kk) {
            bf16x8 a = sA8[(lr << 5) + ((kk * 4 + lk) ^ (lr & 7))];
            acc[0] = __builtin_amdgcn_mfma_f32_16x16x32_bf16(bw1[kk][0], a, acc[0], 0, 0, 0);
            acc[1] = __builtin_amdgcn_mfma_f32_16x16x32_bf16(bw1[kk][1], a, acc[1], 0, 0, 0);
        }
        __syncthreads();   // all sA reads done before H overwrites low 4KB

        // bn+relu, H (bf16) -> sH = sAd[0..4KB), [16 r][16 g] swizzled
        #pragma unroll
        for (int ni = 0; ni < 2; ++ni) {
            int c0 = wc + ni * 16 + lk * 4;
            int g = c0 >> 3;
            int sub = (c0 & 4) ? 8 : 0;
            float h0 = fmaxf(acc[ni][0] * scv[ni].x + shv[ni].x, 0.f);
            float h1 = fmaxf(acc[ni][1] * scv[ni].y + shv[ni].y, 0.f);
            float h2 = fmaxf(acc[ni][2] * scv[ni].z + shv[ni].z, 0.f);
            float h3 = fmaxf(acc[ni][3] * scv[ni].w + shv[ni].w, 0.f);
            uint2 o;
            o.x = (unsigned)f2bf(h0) | ((unsigned)f2bf(h1) << 16);
            o.y = (unsigned)f2bf(h2) | ((unsigned)f2bf(h3) << 16);
            *(uint2*)((char*)sAd + (((lr << 4) + (g ^ (lr & 7))) << 4) + sub) = o;
        }
        __syncthreads();

        // MFMA2: [Q|R] = H @ W2T2^T ; wave w -> cols [32w, 32w+32)
        f32x4 acc2[2];
        acc2[0] = (f32x4){0.f, 0.f, 0.f, 0.f};
        acc2[1] = (f32x4){0.f, 0.f, 0.f, 0.f};

        #pragma unroll
        for (int kk = 0; kk < 4; ++kk) {
            bf16x8 a = *(const bf16x8*)((const char*)sAd +
                                        (((lr << 4) + ((kk * 4 + lk) ^ (lr & 7))) << 4));
            acc2[0] = __builtin_amdgcn_mfma_f32_16x16x32_bf16(bw2[kk][0], a, acc2[0], 0, 0, 0);
            acc2[1] = __builtin_amdgcn_mfma_f32_16x16x32_bf16(bw2[kk][1], a, acc2[1], 0, 0, 0);
        }

        const int rowo = row0 + lr;
        if (rowo < N_NODES) {
            #pragma unroll
            for (int ni = 0; ni < 2; ++ni) {
                int cw = wc + ni * 16 + lk * 4;
                if (cw < 64) {
                    ushort4 o;
                    o.x = f2bf(acc2[ni][0]); o.y = f2bf(acc2[ni][1]);
                    o.z = f2bf(acc2[ni][2]); o.w = f2bf(acc2[ni][3]);
                    *(ushort4*)(Q + ((size_t)rowo << 6) + cw) = o;
                } else {
                    int c0 = cw - 64;
                    float4 bias = *(const float4*)(b2 + c0);
                    float4 o;
                    o.x = acc2[ni][0] + bias.x; o.y = acc2[ni][1] + bias.y;
                    o.z = acc2[ni][2] + bias.z; o.w = acc2[ni][3] + bias.w;
                    *(float4*)(R + ((size_t)rowo << 6) + c0) = o;
                }
            }
        }
        __syncthreads();   // sH reads done before next tile's stage overwrites
    }
}

// ===========================================================================
// finish: out[n] = mean_j Q[j] + R[n].  Quarter-bucket scan (R10 loop form).
// ===========================================================================
__global__ __launch_bounds__(256) void finish_kernel(
    const ushort* __restrict__ Q, const float* __restrict__ R,
    const unsigned* __restrict__ bucket, const int* __restrict__ bcnt,
    float* __restrict__ out) {
    __shared__ ushort lell[16 * ELL_MAX];   // 2 KB
    __shared__ int lcnt[16];
    const int tid = threadIdx.x;
    const int bkt = blockIdx.x >> 2, q = blockIdx.x & 3;

    if (tid < 16) lcnt[tid] = 0;
    int n = bcnt[bkt];
    if (n > BUCKET_CAP) n = BUCKET_CAP;
    __syncthreads();
    for (int i = tid; i < n; i += 256) {
        unsigned u = bucket[(size_t)bkt * BUCKET_CAP + i];
        int dl = u & 63;
        if ((dl >> 4) == q) {
            int r = dl & 15;
            int p = atomicAdd(&lcnt[r], 1);
            if (p < ELL_MAX) lell[(r << 6) + p] = (ushort)(u >> 6);
        }
    }
    __syncthreads();

    const int grp = tid >> 4, lane16 = tid & 15;
    const int node = (bkt << 6) + (q << 4) + grp;
    if (node >= N_NODES) return;
    const int dg = lcnt[grp];
    const int end = dg < ELL_MAX ? dg : ELL_MAX;
    const ushort* Lp = lell + (grp << 6);
    float a0 = 0.f, a1 = 0.f, a2 = 0.f, a3 = 0.f;
    int j = 0;
    for (; j + 8 <= end; j += 8) {
        ushort4 sa = *(const ushort4*)(Lp + j);
        ushort4 sb = *(const ushort4*)(Lp + j + 4);
        uint2 u0 = *(const uint2*)(Q + ((size_t)sa.x << 6) + lane16 * 4);
        uint2 u1 = *(const uint2*)(Q + ((size_t)sa.y << 6) + lane16 * 4);
        uint2 u2 = *(const uint2*)(Q + ((size_t)sa.z << 6) + lane16 * 4);
        uint2 u3 = *(const uint2*)(Q + ((size_t)sa.w << 6) + lane16 * 4);
        uint2 u4 = *(const uint2*)(Q + ((size_t)sb.x << 6) + lane16 * 4);
        uint2 u5 = *(const uint2*)(Q + ((size_t)sb.y << 6) + lane16 * 4);
        uint2 u6 = *(const uint2*)(Q + ((size_t)sb.z << 6) + lane16 * 4);
        uint2 u7 = *(const uint2*)(Q + ((size_t)sb.w << 6) + lane16 * 4);
        a0 += bf_lo(u0.x) + bf_lo(u1.x) + bf_lo(u2.x) + bf_lo(u3.x)
            + bf_lo(u4.x) + bf_lo(u5.x) + bf_lo(u6.x) + bf_lo(u7.x);
        a1 += bf_hi(u0.x) + bf_hi(u1.x) + bf_hi(u2.x) + bf_hi(u3.x)
            + bf_hi(u4.x) + bf_hi(u5.x) + bf_hi(u6.x) + bf_hi(u7.x);
        a2 += bf_lo(u0.y) + bf_lo(u1.y) + bf_lo(u2.y) + bf_lo(u3.y)
            + bf_lo(u4.y) + bf_lo(u5.y) + bf_lo(u6.y) + bf_lo(u7.y);
        a3 += bf_hi(u0.y) + bf_hi(u1.y) + bf_hi(u2.y) + bf_hi(u3.y)
            + bf_hi(u4.y) + bf_hi(u5.y) + bf_hi(u6.y) + bf_hi(u7.y);
    }
    for (; j + 4 <= end; j += 4) {
        ushort4 ss = *(const ushort4*)(Lp + j);
        uint2 u0 = *(const uint2*)(Q + ((size_t)ss.x << 6) + lane16 * 4);
        uint2 u1 = *(const uint2*)(Q + ((size_t)ss.y << 6) + lane16 * 4);
        uint2 u2 = *(const uint2*)(Q + ((size_t)ss.z << 6) + lane16 * 4);
        uint2 u3 = *(const uint2*)(Q + ((size_t)ss.w << 6) + lane16 * 4);
        a0 += bf_lo(u0.x) + bf_lo(u1.x) + bf_lo(u2.x) + bf_lo(u3.x);
        a1 += bf_hi(u0.x) + bf_hi(u1.x) + bf_hi(u2.x) + bf_hi(u3.x);
        a2 += bf_lo(u0.y) + bf_lo(u1.y) + bf_lo(u2.y) + bf_lo(u3.y);
        a3 += bf_hi(u0.y) + bf_hi(u1.y) + bf_hi(u2.y) + bf_hi(u3.y);
    }
    for (; j < end; ++j) {
        int s = Lp[j];
        uint2 u = *(const uint2*)(Q + ((size_t)s << 6) + lane16 * 4);
        a0 += bf_lo(u.x); a1 += bf_hi(u.x);
        a2 += bf_lo(u.y); a3 += bf_hi(u.y);
    }
    float ic = 1.0f / fmaxf((float)dg, 1.0f);
    float4 r4 = *(const float4*)(R + ((size_t)node << 6) + lane16 * 4);
    float4 o;
    o.x = a0 * ic + r4.x;
    o.y = a1 * ic + r4.y;
    o.z = a2 * ic + r4.z;
    o.w = a3 * ic + r4.w;
    *(float4*)(out + ((size_t)node << 6) + lane16 * 4) = o;
}

// ---------------------------------------------------------------------------
extern "C" void kernel_launch(void* const* d_in, const int* in_sizes, int n_in,
                              void* d_out, int out_size, void* d_ws, size_t ws_size,
                              hipStream_t stream) {
    const float* x     = (const float*)d_in[0];
    const int*   eidx  = (const int*)d_in[1];
    const float* W1_l  = (const float*)d_in[2];
    const float* W1_r  = (const float*)d_in[3];
    const float* b1    = (const float*)d_in[4];
    const float* gamma = (const float*)d_in[5];
    const float* beta  = (const float*)d_in[6];
    const float* mean  = (const float*)d_in[7];
    const float* var   = (const float*)d_in[8];
    const float* W2_l  = (const float*)d_in[9];
    const float* W2_r  = (const float*)d_in[10];
    const float* b2    = (const float*)d_in[11];
    float* out = (float*)d_out;

    char* p = (char*)d_ws;
    ushort* Xb   = (ushort*)p; p += (size_t)N_NODES * 128 * 2;            // 12.8 MB
    ushort* Agg  = (ushort*)p; p += (size_t)N_NODES * 128 * 2;            // 12.8 MB
    ushort* Q    = (ushort*)p; p += (size_t)N_NODES * 64 * 2;             //  6.4 MB
    float*  R    = (float*)p;  p += (size_t)N_NODES * 64 * 4;             // 12.8 MB
    ushort* W1T  = (ushort*)p; p += 128 * 256 * 2;
    ushort* W2T2 = (ushort*)p; p += 128 * 128 * 2;
    float* scale_ = (float*)p; p += 128 * 4;
    float* shift_ = (float*)p; p += 128 * 4;
    unsigned* bucket = (unsigned*)p; p += (size_t)N_BUCKETS * BUCKET_CAP * 4; // 3.2 MB
    int* bcnt    = (int*)p;    p += (size_t)N_BUCKETS * 4;                // 3.1 KB

    zero_bcnt_kernel<<<(N_BUCKETS + 255) / 256, 256, 0, stream>>>(bcnt);

    prep_scatter_kernel<<<PREP_GRID, 256, 0, stream>>>(
        x, eidx, W1_l, W1_r, W2_l, W2_r, gamma, beta, mean, var, b1,
        Xb, W1T, W2T2, scale_, shift_, bcnt, bucket);

    gather1_kernel<<<N_BUCKETS * 4, 256, 0, stream>>>(Xb, bucket, bcnt, Agg);

    mm_kernel<<<MM_GRID, 256, 0, stream>>>(
        Agg, Xb, W1T, W2T2, scale_, shift_, b2, Q, R);

    finish_kernel<<<N_BUCKETS * 4, 256, 0, stream>>>(Q, R, bucket, bcnt, out);
}

// Round 15
// 87.999 us; speedup vs baseline: 1.2680x; 1.0430x over previous
//
#include <hip/hip_runtime.h>
#include <hip/hip_bf16.h>

#define N_NODES 50000
#define N_EDGES 600000
#define BN_EPS 1e-5f
#define ELL_MAX 64          // per-node list cap; P(deg>=64) ~ 1e-30
#define N_BUCKETS 782       // ceil(50000/64) 64-node tiles
#define BUCKET_CAP 1024     // lambda=768, sigma=27.7 -> +9.2 sigma

#define EPT 8               // edges per thread in the binning blocks
#define EB_EDGES (256 * EPT)                    // 2048
#define N_EB ((N_EDGES + EB_EDGES - 1) / EB_EDGES)   // 293
#define N_CONV_BLK 6250                         // 1.6M threads / 256
#define N_W_BLK 192                             // 49152 / 256
#define PREP_GRID (N_EB + N_CONV_BLK + N_W_BLK + 1)

#define N_TILES 3125        // 50000 / 16
#define MM_GRID 1024        // 4 blocks/CU; each block ~3 tiles, weights loaded once

typedef short bf16x8 __attribute__((ext_vector_type(8)));
typedef float f32x4 __attribute__((ext_vector_type(4)));

__device__ __forceinline__ ushort f2bf(float f) {
    unsigned u = __float_as_uint(f);
    u += 0x7fffu + ((u >> 16) & 1u);
    return (ushort)(u >> 16);
}
__device__ __forceinline__ float bf_lo(unsigned u) { return __uint_as_float(u << 16); }
__device__ __forceinline__ float bf_hi(unsigned u) { return __uint_as_float(u & 0xffff0000u); }

// ===========================================================================
// zero_bcnt: hand-rolled (runtime tiny-fill path avoided).
// ===========================================================================
__global__ __launch_bounds__(256) void zero_bcnt_kernel(int* __restrict__ bcnt) {
    int t = blockIdx.x * 256 + threadIdx.x;
    if (t < N_BUCKETS) bcnt[t] = 0;
}

// ===========================================================================
// prep_scatter (block-range partitioned):
//   blocks [0, N_EB): LDS-aggregated edge binning, 2048 edges/block.
//   blocks [N_EB, +6250): x -> bf16 (Xb).
//   blocks [.., +192): weight transpose W1T / W2T2.
//   last block: bn fold.
// ===========================================================================
__global__ __launch_bounds__(256) void prep_scatter_kernel(
    const float* __restrict__ x, const int* __restrict__ eidx,
    const float* __restrict__ W1l, const float* __restrict__ W1r,
    const float* __restrict__ W2l, const float* __restrict__ W2r,
    const float* __restrict__ gamma, const float* __restrict__ beta,
    const float* __restrict__ mean, const float* __restrict__ var,
    const float* __restrict__ b1,
    ushort* __restrict__ Xb, ushort* __restrict__ W1T, ushort* __restrict__ W2T2,
    float* __restrict__ scale_, float* __restrict__ shift_,
    int* __restrict__ bcnt, unsigned* __restrict__ bucket) {
    const int blk = blockIdx.x;
    const int tid = threadIdx.x;

    if (blk < N_EB) {
        __shared__ int lcnt[N_BUCKETS];
        __shared__ int lbase[N_BUCKETS];
        const int e0 = blk * EB_EDGES;
        const int n = (N_EDGES - e0) < EB_EDGES ? (N_EDGES - e0) : EB_EDGES;

        for (int i = tid; i < N_BUCKETS; i += 256) lcnt[i] = 0;
        __syncthreads();

        // E1: histogram + rank; keep pk and packed src in registers
        unsigned pk[EPT];
        unsigned sp[EPT / 2];
        #pragma unroll
        for (int i = 0; i < EPT; ++i) {
            int idx = i * 256 + tid;
            if (idx < n) {
                int src = eidx[e0 + idx];
                int dst = eidx[N_EDGES + e0 + idx];
                int b = dst >> 6;
                int r = atomicAdd(&lcnt[b], 1);
                pk[i] = ((unsigned)b << 17) | ((unsigned)r << 6) | (unsigned)(dst & 63);
                if (i & 1) sp[i >> 1] |= ((unsigned)src << 16);
                else       sp[i >> 1]  = (unsigned)src & 0xFFFFu;
            } else {
                pk[i] = 0xFFFFFFFFu;
            }
        }
        __syncthreads();

        // E2: one global atomic per non-empty bin
        for (int i = tid; i < N_BUCKETS; i += 256) {
            int c = lcnt[i];
            lbase[i] = c ? atomicAdd(&bcnt[i], c) : 0;
        }
        __syncthreads();

        // E3: grouped scatter from registers
        #pragma unroll
        for (int i = 0; i < EPT; ++i) {
            if (pk[i] != 0xFFFFFFFFu) {
                int b = pk[i] >> 17;
                int r = (pk[i] >> 6) & 0x7FF;
                int dl = pk[i] & 63;
                unsigned src = (i & 1) ? (sp[i >> 1] >> 16) : (sp[i >> 1] & 0xFFFFu);
                int p = lbase[b] + r;
                if (p < BUCKET_CAP)
                    bucket[(size_t)b * BUCKET_CAP + p] = (src << 6) | (unsigned)dl;
            }
        }
    } else if (blk < N_EB + N_CONV_BLK) {
        int t = (blk - N_EB) * 256 + tid;           // < 1,600,000
        int row = t >> 5, c4 = t & 31;
        float4 v = *(const float4*)(x + (size_t)row * 128 + c4 * 4);
        ushort4 o;
        o.x = f2bf(v.x); o.y = f2bf(v.y); o.z = f2bf(v.z); o.w = f2bf(v.w);
        *(ushort4*)(Xb + (size_t)row * 128 + c4 * 4) = o;
    } else if (blk < N_EB + N_CONV_BLK + N_W_BLK) {
        int t2 = (blk - N_EB - N_CONV_BLK) * 256 + tid;   // < 49152
        if (t2 < 128 * 256) {
            int c = t2 >> 8, k = t2 & 255;
            float v = (k < 128) ? W1l[k * 128 + c] : W1r[(k - 128) * 128 + c];
            W1T[c * 256 + k] = f2bf(v);
        } else {
            int t3 = t2 - 128 * 256;            // 0..16383
            int c = t3 >> 7, k = t3 & 127;
            float v = (c < 64) ? W2l[k * 64 + c] : W2r[k * 64 + (c - 64)];
            W2T2[c * 128 + k] = f2bf(v);
        }
    } else {
        if (tid < 128) {
            int c = tid;
            float sc = gamma[c] * rsqrtf(var[c] + BN_EPS);
            scale_[c] = sc;
            shift_[c] = sc * (b1[c] - mean[c]) + beta[c];
        }
    }
}

// ===========================================================================
// gather1: one block per QUARTER-bucket (16 nodes). Scan the bucket's list
// into a 2KB LDS 16-node list, then gather-mean from Xb (R10 loop form).
// ===========================================================================
__global__ __launch_bounds__(256) void gather1_kernel(
    const ushort* __restrict__ Xb, const unsigned* __restrict__ bucket,
    const int* __restrict__ bcnt, ushort* __restrict__ Agg) {
    __shared__ ushort lell[16 * ELL_MAX];   // 2 KB
    __shared__ int lcnt[16];
    const int tid = threadIdx.x;
    const int bkt = blockIdx.x >> 2, q = blockIdx.x & 3;

    if (tid < 16) lcnt[tid] = 0;
    int n = bcnt[bkt];
    if (n > BUCKET_CAP) n = BUCKET_CAP;
    __syncthreads();
    for (int i = tid; i < n; i += 256) {
        unsigned u = bucket[(size_t)bkt * BUCKET_CAP + i];
        int dl = u & 63;
        if ((dl >> 4) == q) {
            int r = dl & 15;
            int p = atomicAdd(&lcnt[r], 1);
            if (p < ELL_MAX) lell[(r << 6) + p] = (ushort)(u >> 6);
        }
    }
    __syncthreads();

    const int grp = tid >> 4, lane16 = tid & 15;
    const int node = (bkt << 6) + (q << 4) + grp;
    if (node >= N_NODES) return;
    const int dg = lcnt[grp];
    const int end = dg < ELL_MAX ? dg : ELL_MAX;
    const ushort* Lp = lell + (grp << 6);
    float a0 = 0.f, a1 = 0.f, a2 = 0.f, a3 = 0.f;
    float a4 = 0.f, a5 = 0.f, a6 = 0.f, a7 = 0.f;
    int j = 0;
    for (; j + 8 <= end; j += 8) {
        ushort4 sa = *(const ushort4*)(Lp + j);
        ushort4 sb = *(const ushort4*)(Lp + j + 4);
        uint4 u0 = *(const uint4*)(Xb + ((size_t)sa.x << 7) + lane16 * 8);
        uint4 u1 = *(const uint4*)(Xb + ((size_t)sa.y << 7) + lane16 * 8);
        uint4 u2 = *(const uint4*)(Xb + ((size_t)sa.z << 7) + lane16 * 8);
        uint4 u3 = *(const uint4*)(Xb + ((size_t)sa.w << 7) + lane16 * 8);
        uint4 u4 = *(const uint4*)(Xb + ((size_t)sb.x << 7) + lane16 * 8);
        uint4 u5 = *(const uint4*)(Xb + ((size_t)sb.y << 7) + lane16 * 8);
        uint4 u6 = *(const uint4*)(Xb + ((size_t)sb.z << 7) + lane16 * 8);
        uint4 u7 = *(const uint4*)(Xb + ((size_t)sb.w << 7) + lane16 * 8);
        a0 += bf_lo(u0.x) + bf_lo(u1.x) + bf_lo(u2.x) + bf_lo(u3.x)
            + bf_lo(u4.x) + bf_lo(u5.x) + bf_lo(u6.x) + bf_lo(u7.x);
        a1 += bf_hi(u0.x) + bf_hi(u1.x) + bf_hi(u2.x) + bf_hi(u3.x)
            + bf_hi(u4.x) + bf_hi(u5.x) + bf_hi(u6.x) + bf_hi(u7.x);
        a2 += bf_lo(u0.y) + bf_lo(u1.y) + bf_lo(u2.y) + bf_lo(u3.y)
            + bf_lo(u4.y) + bf_lo(u5.y) + bf_lo(u6.y) + bf_lo(u7.y);
        a3 += bf_hi(u0.y) + bf_hi(u1.y) + bf_hi(u2.y) + bf_hi(u3.y)
            + bf_hi(u4.y) + bf_hi(u5.y) + bf_hi(u6.y) + bf_hi(u7.y);
        a4 += bf_lo(u0.z) + bf_lo(u1.z) + bf_lo(u2.z) + bf_lo(u3.z)
            + bf_lo(u4.z) + bf_lo(u5.z) + bf_lo(u6.z) + bf_lo(u7.z);
        a5 += bf_hi(u0.z) + bf_hi(u1.z) + bf_hi(u2.z) + bf_hi(u3.z)
            + bf_hi(u4.z) + bf_hi(u5.z) + bf_hi(u6.z) + bf_hi(u7.z);
        a6 += bf_lo(u0.w) + bf_lo(u1.w) + bf_lo(u2.w) + bf_lo(u3.w)
            + bf_lo(u4.w) + bf_lo(u5.w) + bf_lo(u6.w) + bf_lo(u7.w);
        a7 += bf_hi(u0.w) + bf_hi(u1.w) + bf_hi(u2.w) + bf_hi(u3.w)
            + bf_hi(u4.w) + bf_hi(u5.w) + bf_hi(u6.w) + bf_hi(u7.w);
    }
    for (; j + 4 <= end; j += 4) {
        ushort4 sa = *(const ushort4*)(Lp + j);
        uint4 u0 = *(const uint4*)(Xb + ((size_t)sa.x << 7) + lane16 * 8);
        uint4 u1 = *(const uint4*)(Xb + ((size_t)sa.y << 7) + lane16 * 8);
        uint4 u2 = *(const uint4*)(Xb + ((size_t)sa.z << 7) + lane16 * 8);
        uint4 u3 = *(const uint4*)(Xb + ((size_t)sa.w << 7) + lane16 * 8);
        a0 += bf_lo(u0.x) + bf_lo(u1.x) + bf_lo(u2.x) + bf_lo(u3.x);
        a1 += bf_hi(u0.x) + bf_hi(u1.x) + bf_hi(u2.x) + bf_hi(u3.x);
        a2 += bf_lo(u0.y) + bf_lo(u1.y) + bf_lo(u2.y) + bf_lo(u3.y);
        a3 += bf_hi(u0.y) + bf_hi(u1.y) + bf_hi(u2.y) + bf_hi(u3.y);
        a4 += bf_lo(u0.z) + bf_lo(u1.z) + bf_lo(u2.z) + bf_lo(u3.z);
        a5 += bf_hi(u0.z) + bf_hi(u1.z) + bf_hi(u2.z) + bf_hi(u3.z);
        a6 += bf_lo(u0.w) + bf_lo(u1.w) + bf_lo(u2.w) + bf_lo(u3.w);
        a7 += bf_hi(u0.w) + bf_hi(u1.w) + bf_hi(u2.w) + bf_hi(u3.w);
    }
    for (; j < end; ++j) {
        int s = Lp[j];
        uint4 u = *(const uint4*)(Xb + ((size_t)s << 7) + lane16 * 8);
        a0 += bf_lo(u.x); a1 += bf_hi(u.x);
        a2 += bf_lo(u.y); a3 += bf_hi(u.y);
        a4 += bf_lo(u.z); a5 += bf_hi(u.z);
        a6 += bf_lo(u.w); a7 += bf_hi(u.w);
    }
    float ic = 1.0f / fmaxf((float)dg, 1.0f);
    uint4 o;
    o.x = (unsigned)f2bf(a0 * ic) | ((unsigned)f2bf(a1 * ic) << 16);
    o.y = (unsigned)f2bf(a2 * ic) | ((unsigned)f2bf(a3 * ic) << 16);
    o.z = (unsigned)f2bf(a4 * ic) | ((unsigned)f2bf(a5 * ic) << 16);
    o.w = (unsigned)f2bf(a6 * ic) | ((unsigned)f2bf(a7 * ic) << 16);
    *(uint4*)(Agg + ((size_t)node << 7) + lane16 * 8) = o;
}

// ===========================================================================
// mm: grid-stride over 16-row tiles, 1024 blocks, weights register-pinned
// (R14). NEW: software-pipelined A-stage (T14 issue-early/write-late) --
// tile t+MM_GRID's global loads are issued right after tile t's LDS-write
// barrier and ride out MFMA1/bn/MFMA2/store, so stage L3 latency (cross-XCD
// dirty Agg lines, ~600-900cyc) leaves the critical path.
// ===========================================================================
__global__ __launch_bounds__(256) void mm_kernel(
    const ushort* __restrict__ Agg, const ushort* __restrict__ Xb,
    const ushort* __restrict__ W1T, const ushort* __restrict__ W2T2,
    const float* __restrict__ scale_, const float* __restrict__ shift_,
    const float* __restrict__ b2,
    ushort* __restrict__ Q, float* __restrict__ R) {
    __shared__ unsigned sAd[16 * 32 * 4];   // 8 KB
    const int tid = threadIdx.x;
    const int w = tid >> 6, l = tid & 63;
    const int wc = w << 5;              // 0,32,64,96
    const int lr = l & 15, lk = l >> 4;

    // ---- load all weight fragments ONCE (loop-invariant across tiles) ----
    bf16x8 bw1[8][2];
    #pragma unroll
    for (int kk = 0; kk < 8; ++kk)
        #pragma unroll
        for (int ni = 0; ni < 2; ++ni)
            bw1[kk][ni] = *(const bf16x8*)(W1T +
                (size_t)(wc + ni * 16 + lr) * 256 + kk * 32 + lk * 8);
    bf16x8 bw2[4][2];
    #pragma unroll
    for (int kk = 0; kk < 4; ++kk)
        #pragma unroll
        for (int ni = 0; ni < 2; ++ni)
            bw2[kk][ni] = *(const bf16x8*)(W2T2 +
                (size_t)(wc + ni * 16 + lr) * 128 + kk * 32 + lk * 8);

    // ---- bn params (also loop-invariant) ----
    float4 scv[2], shv[2];
    #pragma unroll
    for (int ni = 0; ni < 2; ++ni) {
        int c0 = wc + ni * 16 + lk * 4;
        scv[ni] = *(const float4*)(scale_ + c0);
        shv[ni] = *(const float4*)(shift_ + c0);
    }

    const bf16x8* sA8 = (const bf16x8*)sAd;
    // stage coords (fixed per thread): granules g = tid and 256+tid
    const int r0_ = tid >> 5,        g0_ = tid & 31;
    const int r1_ = (256 + tid) >> 5, g1_ = (256 + tid) & 31;

    // ---- prologue: load tile blockIdx.x's A-rows into registers ----
    uint4 sv0, sv1;
    {
        int row0 = blockIdx.x << 4;
        int rowa = row0 + r0_, rowb = row0 + r1_;
        sv0 = make_uint4(0, 0, 0, 0);
        sv1 = make_uint4(0, 0, 0, 0);
        if (rowa < N_NODES)
            sv0 = *(const uint4*)((g0_ < 16)
                ? (Agg + ((size_t)rowa << 7) + g0_ * 8)
                : (Xb + ((size_t)rowa << 7) + (g0_ - 16) * 8));
        if (rowb < N_NODES)
            sv1 = *(const uint4*)((g1_ < 16)
                ? (Agg + ((size_t)rowb << 7) + g1_ * 8)
                : (Xb + ((size_t)rowb << 7) + (g1_ - 16) * 8));
    }

    for (int t = blockIdx.x; t < N_TILES; t += MM_GRID) {
        const int row0 = t << 4;

        // write staged regs -> LDS (swizzled), then barrier
        *(uint4*)&sAd[((r0_ << 5) + (g0_ ^ (r0_ & 7))) << 2] = sv0;
        *(uint4*)&sAd[((r1_ << 5) + (g1_ ^ (r1_ & 7))) << 2] = sv1;
        __syncthreads();

        // issue NEXT tile's loads now; they complete under the MFMAs below
        const int tn = t + MM_GRID;
        uint4 nv0 = make_uint4(0, 0, 0, 0), nv1 = make_uint4(0, 0, 0, 0);
        if (tn < N_TILES) {
            int nrow0 = tn << 4;
            int rowa = nrow0 + r0_, rowb = nrow0 + r1_;
            if (rowa < N_NODES)
                nv0 = *(const uint4*)((g0_ < 16)
                    ? (Agg + ((size_t)rowa << 7) + g0_ * 8)
                    : (Xb + ((size_t)rowa << 7) + (g0_ - 16) * 8));
            if (rowb < N_NODES)
                nv1 = *(const uint4*)((g1_ < 16)
                    ? (Agg + ((size_t)rowb << 7) + g1_ * 8)
                    : (Xb + ((size_t)rowb << 7) + (g1_ - 16) * 8));
        }

        f32x4 acc[2];
        acc[0] = (f32x4){0.f, 0.f, 0.f, 0.f};
        acc[1] = (f32x4){0.f, 0.f, 0.f, 0.f};

        #pragma unroll
        for (int kk = 0; kk < 8; ++kk) {
            bf16x8 a = sA8[(lr << 5) + ((kk * 4 + lk) ^ (lr & 7))];
            acc[0] = __builtin_amdgcn_mfma_f32_16x16x32_bf16(bw1[kk][0], a, acc[0], 0, 0, 0);
            acc[1] = __builtin_amdgcn_mfma_f32_16x16x32_bf16(bw1[kk][1], a, acc[1], 0, 0, 0);
        }
        __syncthreads();   // all sA reads done before H overwrites low 4KB

        // bn+relu, H (bf16) -> sH = sAd[0..4KB), [16 r][16 g] swizzled
        #pragma unroll
        for (int ni = 0; ni < 2; ++ni) {
            int c0 = wc + ni * 16 + lk * 4;
            int g = c0 >> 3;
            int sub = (c0 & 4) ? 8 : 0;
            float h0 = fmaxf(acc[ni][0] * scv[ni].x + shv[ni].x, 0.f);
            float h1 = fmaxf(acc[ni][1] * scv[ni].y + shv[ni].y, 0.f);
            float h2 = fmaxf(acc[ni][2] * scv[ni].z + shv[ni].z, 0.f);
            float h3 = fmaxf(acc[ni][3] * scv[ni].w + shv[ni].w, 0.f);
            uint2 o;
            o.x = (unsigned)f2bf(h0) | ((unsigned)f2bf(h1) << 16);
            o.y = (unsigned)f2bf(h2) | ((unsigned)f2bf(h3) << 16);
            *(uint2*)((char*)sAd + (((lr << 4) + (g ^ (lr & 7))) << 4) + sub) = o;
        }
        __syncthreads();

        // MFMA2: [Q|R] = H @ W2T2^T ; wave w -> cols [32w, 32w+32)
        f32x4 acc2[2];
        acc2[0] = (f32x4){0.f, 0.f, 0.f, 0.f};
        acc2[1] = (f32x4){0.f, 0.f, 0.f, 0.f};

        #pragma unroll
        for (int kk = 0; kk < 4; ++kk) {
            bf16x8 a = *(const bf16x8*)((const char*)sAd +
                                        (((lr << 4) + ((kk * 4 + lk) ^ (lr & 7))) << 4));
            acc2[0] = __builtin_amdgcn_mfma_f32_16x16x32_bf16(bw2[kk][0], a, acc2[0], 0, 0, 0);
            acc2[1] = __builtin_amdgcn_mfma_f32_16x16x32_bf16(bw2[kk][1], a, acc2[1], 0, 0, 0);
        }

        const int rowo = row0 + lr;
        if (rowo < N_NODES) {
            #pragma unroll
            for (int ni = 0; ni < 2; ++ni) {
                int cw = wc + ni * 16 + lk * 4;
                if (cw < 64) {
                    ushort4 o;
                    o.x = f2bf(acc2[ni][0]); o.y = f2bf(acc2[ni][1]);
                    o.z = f2bf(acc2[ni][2]); o.w = f2bf(acc2[ni][3]);
                    *(ushort4*)(Q + ((size_t)rowo << 6) + cw) = o;
                } else {
                    int c0 = cw - 64;
                    float4 bias = *(const float4*)(b2 + c0);
                    float4 o;
                    o.x = acc2[ni][0] + bias.x; o.y = acc2[ni][1] + bias.y;
                    o.z = acc2[ni][2] + bias.z; o.w = acc2[ni][3] + bias.w;
                    *(float4*)(R + ((size_t)rowo << 6) + c0) = o;
                }
            }
        }
        __syncthreads();   // sH reads done before next tile's stage overwrites

        sv0 = nv0; sv1 = nv1;
    }
}

// ===========================================================================
// finish: out[n] = mean_j Q[j] + R[n].  Quarter-bucket scan (R10 loop form).
// ===========================================================================
__global__ __launch_bounds__(256) void finish_kernel(
    const ushort* __restrict__ Q, const float* __restrict__ R,
    const unsigned* __restrict__ bucket, const int* __restrict__ bcnt,
    float* __restrict__ out) {
    __shared__ ushort lell[16 * ELL_MAX];   // 2 KB
    __shared__ int lcnt[16];
    const int tid = threadIdx.x;
    const int bkt = blockIdx.x >> 2, q = blockIdx.x & 3;

    if (tid < 16) lcnt[tid] = 0;
    int n = bcnt[bkt];
    if (n > BUCKET_CAP) n = BUCKET_CAP;
    __syncthreads();
    for (int i = tid; i < n; i += 256) {
        unsigned u = bucket[(size_t)bkt * BUCKET_CAP + i];
        int dl = u & 63;
        if ((dl >> 4) == q) {
            int r = dl & 15;
            int p = atomicAdd(&lcnt[r], 1);
            if (p < ELL_MAX) lell[(r << 6) + p] = (ushort)(u >> 6);
        }
    }
    __syncthreads();

    const int grp = tid >> 4, lane16 = tid & 15;
    const int node = (bkt << 6) + (q << 4) + grp;
    if (node >= N_NODES) return;
    const int dg = lcnt[grp];
    const int end = dg < ELL_MAX ? dg : ELL_MAX;
    const ushort* Lp = lell + (grp << 6);
    float a0 = 0.f, a1 = 0.f, a2 = 0.f, a3 = 0.f;
    int j = 0;
    for (; j + 8 <= end; j += 8) {
        ushort4 sa = *(const ushort4*)(Lp + j);
        ushort4 sb = *(const ushort4*)(Lp + j + 4);
        uint2 u0 = *(const uint2*)(Q + ((size_t)sa.x << 6) + lane16 * 4);
        uint2 u1 = *(const uint2*)(Q + ((size_t)sa.y << 6) + lane16 * 4);
        uint2 u2 = *(const uint2*)(Q + ((size_t)sa.z << 6) + lane16 * 4);
        uint2 u3 = *(const uint2*)(Q + ((size_t)sa.w << 6) + lane16 * 4);
        uint2 u4 = *(const uint2*)(Q + ((size_t)sb.x << 6) + lane16 * 4);
        uint2 u5 = *(const uint2*)(Q + ((size_t)sb.y << 6) + lane16 * 4);
        uint2 u6 = *(const uint2*)(Q + ((size_t)sb.z << 6) + lane16 * 4);
        uint2 u7 = *(const uint2*)(Q + ((size_t)sb.w << 6) + lane16 * 4);
        a0 += bf_lo(u0.x) + bf_lo(u1.x) + bf_lo(u2.x) + bf_lo(u3.x)
            + bf_lo(u4.x) + bf_lo(u5.x) + bf_lo(u6.x) + bf_lo(u7.x);
        a1 += bf_hi(u0.x) + bf_hi(u1.x) + bf_hi(u2.x) + bf_hi(u3.x)
            + bf_hi(u4.x) + bf_hi(u5.x) + bf_hi(u6.x) + bf_hi(u7.x);
        a2 += bf_lo(u0.y) + bf_lo(u1.y) + bf_lo(u2.y) + bf_lo(u3.y)
            + bf_lo(u4.y) + bf_lo(u5.y) + bf_lo(u6.y) + bf_lo(u7.y);
        a3 += bf_hi(u0.y) + bf_hi(u1.y) + bf_hi(u2.y) + bf_hi(u3.y)
            + bf_hi(u4.y) + bf_hi(u5.y) + bf_hi(u6.y) + bf_hi(u7.y);
    }
    for (; j + 4 <= end; j += 4) {
        ushort4 ss = *(const ushort4*)(Lp + j);
        uint2 u0 = *(const uint2*)(Q + ((size_t)ss.x << 6) + lane16 * 4);
        uint2 u1 = *(const uint2*)(Q + ((size_t)ss.y << 6) + lane16 * 4);
        uint2 u2 = *(const uint2*)(Q + ((size_t)ss.z << 6) + lane16 * 4);
        uint2 u3 = *(const uint2*)(Q + ((size_t)ss.w << 6) + lane16 * 4);
        a0 += bf_lo(u0.x) + bf_lo(u1.x) + bf_lo(u2.x) + bf_lo(u3.x);
        a1 += bf_hi(u0.x) + bf_hi(u1.x) + bf_hi(u2.x) + bf_hi(u3.x);
        a2 += bf_lo(u0.y) + bf_lo(u1.y) + bf_lo(u2.y) + bf_lo(u3.y);
        a3 += bf_hi(u0.y) + bf_hi(u1.y) + bf_hi(u2.y) + bf_hi(u3.y);
    }
    for (; j < end; ++j) {
        int s = Lp[j];
        uint2 u = *(const uint2*)(Q + ((size_t)s << 6) + lane16 * 4);
        a0 += bf_lo(u.x); a1 += bf_hi(u.x);
        a2 += bf_lo(u.y); a3 += bf_hi(u.y);
    }
    float ic = 1.0f / fmaxf((float)dg, 1.0f);
    float4 r4 = *(const float4*)(R + ((size_t)node << 6) + lane16 * 4);
    float4 o;
    o.x = a0 * ic + r4.x;
    o.y = a1 * ic + r4.y;
    o.z = a2 * ic + r4.z;
    o.w = a3 * ic + r4.w;
    *(float4*)(out + ((size_t)node << 6) + lane16 * 4) = o;
}

// ---------------------------------------------------------------------------
extern "C" void kernel_launch(void* const* d_in, const int* in_sizes, int n_in,
                              void* d_out, int out_size, void* d_ws, size_t ws_size,
                              hipStream_t stream) {
    const float* x     = (const float*)d_in[0];
    const int*   eidx  = (const int*)d_in[1];
    const float* W1_l  = (const float*)d_in[2];
    const float* W1_r  = (const float*)d_in[3];
    const float* b1    = (const float*)d_in[4];
    const float* gamma = (const float*)d_in[5];
    const float* beta  = (const float*)d_in[6];
    const float* mean  = (const float*)d_in[7];
    const float* var   = (const float*)d_in[8];
    const float* W2_l  = (const float*)d_in[9];
    const float* W2_r  = (const float*)d_in[10];
    const float* b2    = (const float*)d_in[11];
    float* out = (float*)d_out;

    char* p = (char*)d_ws;
    ushort* Xb   = (ushort*)p; p += (size_t)N_NODES * 128 * 2;            // 12.8 MB
    ushort* Agg  = (ushort*)p; p += (size_t)N_NODES * 128 * 2;            // 12.8 MB
    ushort* Q    = (ushort*)p; p += (size_t)N_NODES * 64 * 2;             //  6.4 MB
    float*  R    = (float*)p;  p += (size_t)N_NODES * 64 * 4;             // 12.8 MB
    ushort* W1T  = (ushort*)p; p += 128 * 256 * 2;
    ushort* W2T2 = (ushort*)p; p += 128 * 128 * 2;
    float* scale_ = (float*)p; p += 128 * 4;
    float* shift_ = (float*)p; p += 128 * 4;
    unsigned* bucket = (unsigned*)p; p += (size_t)N_BUCKETS * BUCKET_CAP * 4; // 3.2 MB
    int* bcnt    = (int*)p;    p += (size_t)N_BUCKETS * 4;                // 3.1 KB

    zero_bcnt_kernel<<<(N_BUCKETS + 255) / 256, 256, 0, stream>>>(bcnt);

    prep_scatter_kernel<<<PREP_GRID, 256, 0, stream>>>(
        x, eidx, W1_l, W1_r, W2_l, W2_r, gamma, beta, mean, var, b1,
        Xb, W1T, W2T2, scale_, shift_, bcnt, bucket);

    gather1_kernel<<<N_BUCKETS * 4, 256, 0, stream>>>(Xb, bucket, bcnt, Agg);

    mm_kernel<<<MM_GRID, 256, 0, stream>>>(
        Agg, Xb, W1T, W2T2, scale_, shift_, b2, Q, R);

    finish_kernel<<<N_BUCKETS * 4, 256, 0, stream>>>(Q, R, bucket, bcnt, out);
}